// Round 17
// baseline (433.263 us; speedup 1.0000x reference)
//
#include <hip/hip_runtime.h>
#include <math.h>

#define N_TOK 32768
#define DIM   512
#define NEXP  64
#define HID   1024
#define CAP   512

typedef float  f32x4  __attribute__((ext_vector_type(4)));
typedef short  bf16x8 __attribute__((ext_vector_type(8)));
typedef unsigned short u16;
typedef unsigned int u32;

#define GET4(v, jj) ((jj) == 0 ? (v).x : (jj) == 1 ? (v).y : (jj) == 2 ? (v).z : (v).w)

__device__ __forceinline__ u16 f2bf(float f) {
  unsigned u = __float_as_uint(f);
  u += 0x7FFFu + ((u >> 16) & 1u);   // RNE
  return (u16)(u >> 16);
}
__device__ __forceinline__ unsigned enc_f(float f) {  // monotone f32 -> u32
  unsigned u = __float_as_uint(f);
  return (u & 0x80000000u) ? ~u : (u | 0x80000000u);
}
__device__ __forceinline__ float dec_f(unsigned k) {
  unsigned u = (k & 0x80000000u) ? (k & 0x7FFFFFFFu) : ~k;
  return __uint_as_float(u);
}
__device__ __forceinline__ void gl16(const u16* g, u16* l) {
  __builtin_amdgcn_global_load_lds(
      (const __attribute__((address_space(1))) unsigned int*)g,
      (__attribute__((address_space(3))) unsigned int*)l, 16, 0, 0);
}
// exact-enough erf (A&S 7.1.26, |eps|<=1.5e-7) -> gelu
__device__ __forceinline__ float gelu_f(float v) {
  float x = fabsf(v) * 0.70710678118654752f;
  float tt = 1.0f / (1.0f + 0.3275911f * x);
  float poly = tt * (0.254829592f + tt * (-0.284496736f + tt * (1.421413741f +
               tt * (-1.453152027f + tt * 1.061405429f))));
  float erfabs = 1.0f - poly * __expf(-x * x);
  float erfv = v >= 0.f ? erfabs : -erfabs;
  return 0.5f * v * (1.0f + erfv);
}

// ---------------- router: LDS-tiled fp32 SGEMM, 64 tok x 64 exp per block ----------------
// Also emits xb = bf16(x) as a by-product.
__global__ __launch_bounds__(256)
void router_kernel(const float* __restrict__ x, const float* __restrict__ rw,
                   float* __restrict__ logitsT, u16* __restrict__ xb) {
  __shared__ float As[32][68];   // [k][m]
  __shared__ float Bs[32][68];   // [k][e]
  const int t = threadIdx.x;
  const int n0 = blockIdx.x * 64;
  const int ty = t >> 4, tx = t & 15;
  const int am = t >> 2, akq = (t & 3) * 8;
  const int bk = t >> 3, beq = (t & 7) * 8;
  const float* xrow = x + (size_t)(n0 + am) * DIM + akq;
  u16* xbrow = xb ? (xb + (size_t)(n0 + am) * DIM + akq) : (u16*)0;
  const float* brow = rw + (size_t)bk * NEXP + beq;

  float acc[4][4] = {};
  for (int k0 = 0; k0 < DIM; k0 += 32) {
    float4 a0 = *(const float4*)(xrow + k0);
    float4 a1 = *(const float4*)(xrow + k0 + 4);
    float4 b0 = *(const float4*)(brow + (size_t)k0 * NEXP);
    float4 b1 = *(const float4*)(brow + (size_t)k0 * NEXP + 4);
    if (xbrow) {
      uint4 o;
      o.x = f2bf(a0.x) | ((unsigned)f2bf(a0.y) << 16);
      o.y = f2bf(a0.z) | ((unsigned)f2bf(a0.w) << 16);
      o.z = f2bf(a1.x) | ((unsigned)f2bf(a1.y) << 16);
      o.w = f2bf(a1.z) | ((unsigned)f2bf(a1.w) << 16);
      *(uint4*)(xbrow + k0) = o;
    }
    __syncthreads();
    As[akq + 0][am] = a0.x; As[akq + 1][am] = a0.y;
    As[akq + 2][am] = a0.z; As[akq + 3][am] = a0.w;
    As[akq + 4][am] = a1.x; As[akq + 5][am] = a1.y;
    As[akq + 6][am] = a1.z; As[akq + 7][am] = a1.w;
    *(float4*)&Bs[bk][beq] = b0;
    *(float4*)&Bs[bk][beq + 4] = b1;
    __syncthreads();
#pragma unroll
    for (int k = 0; k < 32; ++k) {
      float4 av = *(const float4*)&As[k][ty * 4];
      float4 bv = *(const float4*)&Bs[k][tx * 4];
#pragma unroll
      for (int i = 0; i < 4; ++i)
#pragma unroll
        for (int j = 0; j < 4; ++j)
          acc[i][j] += GET4(av, i) * GET4(bv, j);
    }
  }
#pragma unroll
  for (int j = 0; j < 4; ++j) {
    float4 o; o.x = acc[0][j]; o.y = acc[1][j]; o.z = acc[2][j]; o.w = acc[3][j];
    *(float4*)(logitsT + (size_t)(tx * 4 + j) * N_TOK + n0 + ty * 4) = o;
  }
}

// ===================== topk pipeline: T1 hist -> T2 select -> T3 emit =====================
// weights = exp(v)/sum(exp(v))  (no max-shift needed: |v| <= ~4, exp in [0.02, 55], sum < 2e6)

// T1: grid (16,64): block (c,e) histograms 2048 tokens into ghist[e][1024]; psum[e*16+c]
__global__ __launch_bounds__(256)
void topk_hist(const float* __restrict__ logitsT, u32* __restrict__ ghist,
               float* __restrict__ psum) {
  const int c = blockIdx.x, e = blockIdx.y;
  const int t = threadIdx.x, lane = t & 63, wid = t >> 6;
  __shared__ u32 lh[1024];
  __shared__ float wsum[4];
  lh[t] = 0; lh[t + 256] = 0; lh[t + 512] = 0; lh[t + 768] = 0;
  __syncthreads();
  const float* row = logitsT + (size_t)e * N_TOK + c * 2048 + t * 8;
  float4 a = *(const float4*)(row);
  float4 b = *(const float4*)(row + 4);
  float s = 0.f;
#pragma unroll
  for (int j = 0; j < 4; ++j) {
    float v0 = GET4(a, j), v1 = GET4(b, j);
    atomicAdd(&lh[enc_f(v0) >> 22], 1u);
    atomicAdd(&lh[enc_f(v1) >> 22], 1u);
    s += __expf(v0) + __expf(v1);
  }
#pragma unroll
  for (int off = 32; off >= 1; off >>= 1) s += __shfl_xor(s, off);
  if (lane == 0) wsum[wid] = s;
  __syncthreads();
#pragma unroll
  for (int q = 0; q < 4; ++q) {
    const u32 hv = lh[t + q * 256];
    if (hv) atomicAdd(&ghist[e * 1024 + t + q * 256], hv);
  }
  if (t == 0) psum[e * 16 + c] = wsum[0] + wsum[1] + wsum[2] + wsum[3];
}

// T2: 64 blocks (one per expert): find exact ustar + tie bound X; write meta
__global__ __launch_bounds__(256)
void topk_select(const float* __restrict__ logitsT, const u32* __restrict__ ghist,
                 const float* __restrict__ psum, u32* __restrict__ gU,
                 int* __restrict__ gX, float* __restrict__ gZ, u32* __restrict__ gpos,
                 float* __restrict__ auxout) {
  const int e = blockIdx.x;
  const int t = threadIdx.x;
  const float* row = logitsT + (size_t)e * N_TOK;

  __shared__ u32 hist[256];
  __shared__ u32 arr[256], arr2[256];
  __shared__ u32 candK[4096];
  __shared__ int candN[4096];
  __shared__ int tieN[1024];
  __shared__ u32 sh_cnt, sh_b0, sh_rem, sh_chosen, sh_tcnt;
  __shared__ float sh_invZ;

#define SUFFIX_SELECT(NEED) do { \
    if (t < 64) { \
      u32 h0_ = hist[4 * t], h1_ = hist[4 * t + 1], h2_ = hist[4 * t + 2], h3_ = hist[4 * t + 3]; \
      u32 s3_ = h3_, s2_ = h2_ + s3_, s1_ = h1_ + s2_, s0_ = h0_ + s1_; \
      u32 sfx_ = s0_; \
      _Pragma("unroll") for (int off_ = 1; off_ < 64; off_ <<= 1) { \
        u32 o_ = __shfl_down(sfx_, off_); \
        if (t + off_ < 64) sfx_ += o_; } \
      const u32 ex_ = sfx_ - s0_; \
      const u32 S_[4] = {ex_ + s0_, ex_ + s1_, ex_ + s2_, ex_ + s3_}; \
      const u32 Sx_[4] = {ex_ + s1_, ex_ + s2_, ex_ + s3_, ex_}; \
      _Pragma("unroll") for (int k_ = 0; k_ < 4; ++k_) \
        if (S_[k_] >= (NEED) && Sx_[k_] < (NEED)) { sh_chosen = 4 * t + k_; sh_rem = (NEED) - Sx_[k_]; } \
    } \
    __syncthreads(); } while (0)

  // invZ
  if (t == 0) {
    float z = 0.f;
#pragma unroll
    for (int i = 0; i < 16; ++i) z += psum[e * 16 + i];
    sh_invZ = 1.0f / z;
    sh_cnt = 0; sh_tcnt = 0;
  }

  // load ghist: thread t owns buckets 4t..4t+3; group sums -> arr
  const u32 h0 = ghist[e * 1024 + 4 * t + 0];
  const u32 h1 = ghist[e * 1024 + 4 * t + 1];
  const u32 h2 = ghist[e * 1024 + 4 * t + 2];
  const u32 h3 = ghist[e * 1024 + 4 * t + 3];
  arr[t] = h0 + h1 + h2 + h3;
  __syncthreads();
  // wave0: block suffix over 256 groups (lane l owns groups 4l..4l+3)
  if (t < 64) {
    u32 g0 = arr[4 * t], g1 = arr[4 * t + 1], g2 = arr[4 * t + 2], g3 = arr[4 * t + 3];
    u32 s3 = g3, s2 = g2 + s3, s1 = g1 + s2, s0 = g0 + s1;
    u32 sfx = s0;
#pragma unroll
    for (int off = 1; off < 64; off <<= 1) {
      u32 o = __shfl_down(sfx, off);
      if (t + off < 64) sfx += o;
    }
    const u32 ex = sfx - s0;
    arr2[4 * t + 3] = ex;
    arr2[4 * t + 2] = ex + g3;
    arr2[4 * t + 1] = ex + g3 + g2;
    arr2[4 * t + 0] = ex + g3 + g2 + g1;
  }
  __syncthreads();
  // crossing: S_excl(b) < CAP <= S_excl(b)+h[b]
  {
    u32 S = arr2[t];                       // S_excl(4t+3)
    if (S < CAP && S + h3 >= CAP) { sh_b0 = 4 * t + 3; sh_rem = CAP - S; }
    S += h3;
    if (S < CAP && S + h2 >= CAP) { sh_b0 = 4 * t + 2; sh_rem = CAP - S; }
    S += h2;
    if (S < CAP && S + h1 >= CAP) { sh_b0 = 4 * t + 1; sh_rem = CAP - S; }
    S += h1;
    if (S < CAP && S + h0 >= CAP) { sh_b0 = 4 * t + 0; sh_rem = CAP - S; }
  }
  __syncthreads();
  const u32 b0 = sh_b0;
  const u32 rem = sh_rem;

  // collect candidates in bucket b0
  for (int i = 0; i < 32; ++i) {
    const int nb = i * 1024 + t * 4;
    float4 v = *(const float4*)(row + nb);
#pragma unroll
    for (int jj = 0; jj < 4; ++jj) {
      const u32 k = enc_f(GET4(v, jj));
      if ((k >> 22) == b0) {
        const u32 p = atomicAdd(&sh_cnt, 1u);
        if (p < 4096u) { candK[p] = k; candN[p] = nb + jj; }
      }
    }
  }
  __syncthreads();
  const u32 cnt = sh_cnt < 4096u ? sh_cnt : 4096u;

  // radix pass A: bits [21:14]
  if (t < 256) hist[t] = 0;
  __syncthreads();
  for (u32 i = t; i < cnt; i += 256) atomicAdd(&hist[(candK[i] >> 14) & 0xFFu], 1u);
  __syncthreads();
  SUFFIX_SELECT(rem);
  const u32 dA = sh_chosen, remB = sh_rem;
  // pass B: bits [13:6]
  if (t < 256) hist[t] = 0;
  __syncthreads();
  for (u32 i = t; i < cnt; i += 256)
    if (((candK[i] >> 14) & 0xFFu) == dA) atomicAdd(&hist[(candK[i] >> 6) & 0xFFu], 1u);
  __syncthreads();
  SUFFIX_SELECT(remB);
  const u32 dB = sh_chosen, remC = sh_rem;
  // pass C: bits [5:0]
  if (t < 256) hist[t] = 0;
  __syncthreads();
  for (u32 i = t; i < cnt; i += 256)
    if (((candK[i] >> 14) & 0xFFu) == dA && ((candK[i] >> 6) & 0xFFu) == dB)
      atomicAdd(&hist[candK[i] & 0x3Fu], 1u);
  __syncthreads();
  SUFFIX_SELECT(remC);
  const u32 dC = sh_chosen, remF = sh_rem;
  const u32 ustar = (b0 << 22) | (dA << 14) | (dB << 6) | dC;

  // ties: remF-th smallest token index among candK == ustar
  for (u32 i = t; i < cnt; i += 256)
    if (candK[i] == ustar) {
      const u32 p = atomicAdd(&sh_tcnt, 1u);
      if (p < 1024u) tieN[p] = candN[i];
    }
  __syncthreads();
  if (t == 0) {
    const u32 tcnt = sh_tcnt < 1024u ? sh_tcnt : 1024u;
    int last = -1;
    for (u32 r = 0; r < remF; ++r) {
      int mn = 0x7FFFFFFF;
      for (u32 i = 0; i < tcnt; ++i) {
        const int nn = tieN[i];
        if (nn > last && nn < mn) mn = nn;
      }
      last = mn;
    }
    gU[e] = ustar;
    gX[e] = last;
    gZ[e] = sh_invZ;
    gpos[e] = 0;
    if (e == 0) { auxout[0] = 2.44140625e-4f; auxout[1] = 0.015625f; }
  }
#undef SUFFIX_SELECT
}

// T3: grid (16,64): emit selected tokens
__global__ __launch_bounds__(256)
void topk_emit(const float* __restrict__ logitsT, const u32* __restrict__ gU,
               const int* __restrict__ gX, const float* __restrict__ gZ,
               u32* __restrict__ gpos, int* __restrict__ tok_idx,
               float* __restrict__ expw) {
  const int c = blockIdx.x, e = blockIdx.y;
  const int t = threadIdx.x;
  const u32 us = gU[e];
  const int X = gX[e];
  const float iz = gZ[e];
  const int nb = c * 2048 + t * 8;
  const float* row = logitsT + (size_t)e * N_TOK + nb;
  float4 a = *(const float4*)(row);
  float4 b = *(const float4*)(row + 4);
#pragma unroll
  for (int j = 0; j < 8; ++j) {
    const float v = j < 4 ? GET4(a, j) : GET4(b, j - 4);
    const int n = nb + j;
    const u32 k = enc_f(v);
    if (k > us || (k == us && n <= X)) {
      const u32 p = atomicAdd(&gpos[e], 1u);
      tok_idx[e * CAP + p] = n;
      expw[e * CAP + p] = __expf(v) * iz;
    }
  }
}

// ---------------- prep: per-expert transpose+cvt: f32 [E][R][C] -> bf16 [E][C][R] ----------------
__global__ __launch_bounds__(256)
void transpose_cvt_kernel(const float* __restrict__ in, u16* __restrict__ outp,
                          int R, int C) {
  __shared__ u16 tile[64][66];
  const int e = blockIdx.z;
  const int r0 = blockIdx.y * 64, c0 = blockIdx.x * 64;
  const int t = threadIdx.x;
  {
    const int r = t >> 2, cs = (t & 3) * 16;
    const float* ip = in + ((size_t)e * R + (r0 + r)) * C + c0 + cs;
#pragma unroll
    for (int q = 0; q < 4; ++q) {
      float4 v = *(const float4*)(ip + q * 4);
      tile[r][cs + q * 4 + 0] = f2bf(v.x);
      tile[r][cs + q * 4 + 1] = f2bf(v.y);
      tile[r][cs + q * 4 + 2] = f2bf(v.z);
      tile[r][cs + q * 4 + 3] = f2bf(v.w);
    }
  }
  __syncthreads();
  {
    const int c = t >> 2, rs = (t & 3) * 16;
    u16* op = outp + ((size_t)e * C + (c0 + c)) * R + r0 + rs;
    uint4 o0, o1;
    o0.x = tile[rs + 0][c]  | ((unsigned)tile[rs + 1][c]  << 16);
    o0.y = tile[rs + 2][c]  | ((unsigned)tile[rs + 3][c]  << 16);
    o0.z = tile[rs + 4][c]  | ((unsigned)tile[rs + 5][c]  << 16);
    o0.w = tile[rs + 6][c]  | ((unsigned)tile[rs + 7][c]  << 16);
    o1.x = tile[rs + 8][c]  | ((unsigned)tile[rs + 9][c]  << 16);
    o1.y = tile[rs + 10][c] | ((unsigned)tile[rs + 11][c] << 16);
    o1.z = tile[rs + 12][c] | ((unsigned)tile[rs + 13][c] << 16);
    o1.w = tile[rs + 14][c] | ((unsigned)tile[rs + 15][c] << 16);
    *(uint4*)(op) = o0;
    *(uint4*)(op + 8) = o1;
  }
}

// ===================== bf16 GEMMs: BM128 x BN256, BK=32, 3-buf depth-2, 72KB LDS =====================
#define A_EL 4096      // 128*32 elems (8 KB)
#define B_EL 8192      // 256*32 elems (16 KB)

#define LDSW(base, row, hi4v) \
  (*(const bf16x8*)((const char*)(base) + (row) * 64 + ((((hi4v) ^ (((row) >> 1) & 3))) << 4)))

#define STG3(bs, k0) do { \
  gl16(aSrc + (k0), AsmF + (bs) * A_EL + wOff); \
  gl16(bSrc0 + (k0), BsmF + (bs) * B_EL + wOff); \
  gl16(bSrc1 + (k0), BsmF + (bs) * B_EL + wOff + 4096); \
} while (0)

__global__ __launch_bounds__(512, 4)
void fc1_bf(const u16* __restrict__ xb, const int* __restrict__ tok_idx,
            const u16* __restrict__ w1t, const float* __restrict__ b1,
            u16* __restrict__ h) {
  const int p = blockIdx.x;
  const int l = (p & 7) * 128 + (p >> 3);        // bijective XCD remap (1024 = 8*128)
  const int e  = l >> 4;
  const int mt = (l >> 2) & 3;
  const int nt = l & 3;
  const int m0 = mt * 128, n0 = nt * 256;
  const int t = threadIdx.x;
  const int lane = t & 63, wave = t >> 6;        // 8 waves
  const int wm = wave >> 2, wn = wave & 3;       // 2m x 4n, per-wave C 64x64

  __shared__ __align__(16) u16 AsmF[3 * A_EL];   // 24 KB
  __shared__ __align__(16) u16 BsmF[3 * B_EL];   // 48 KB

  const int kc = ((lane & 3) ^ ((lane >> 3) & 3)) * 8;  // pre-swizzled k elem offset
  const int rloc = lane >> 2;                    // 0..15
  const int wOff = wave * 512;                   // 16 rows x 32 elems

  const int arow = wave * 16 + rloc;             // 0..127
  const int tok = tok_idx[e * CAP + m0 + arow];
  const u16* aSrc  = xb + (size_t)tok * DIM + kc;
  const u16* bSrc0 = w1t + ((size_t)e * HID + n0 + arow) * DIM + kc;
  const u16* bSrc1 = w1t + ((size_t)e * HID + n0 + 128 + arow) * DIM + kc;

  f32x4 acc[4][4] = {};
  const int lr = lane & 15, hi4 = lane >> 4;

  STG3(0, 0);     // K-tile 0 -> buf 0
  STG3(1, 32);    // K-tile 1 -> buf 1
  int cur = 0;
  const int KT = DIM / 32;                       // 16
  for (int tt = 0; tt < KT; ++tt) {
    if (tt < KT - 1) asm volatile("s_waitcnt vmcnt(3)" ::: "memory");
    else             asm volatile("s_waitcnt vmcnt(0)" ::: "memory");
    __builtin_amdgcn_s_barrier();
    const u16* Ab = AsmF + cur * A_EL;
    const u16* Bb = BsmF + cur * B_EL;
    bf16x8 af[4], bf[4];
#pragma unroll
    for (int mi = 0; mi < 4; ++mi) af[mi] = LDSW(Ab, wm * 64 + mi * 16 + lr, hi4);
#pragma unroll
    for (int ni = 0; ni < 4; ++ni) bf[ni] = LDSW(Bb, wn * 64 + ni * 16 + lr, hi4);
    if (tt + 2 < KT) {
      const int bs = (tt + 2) % 3;
      STG3(bs, (tt + 2) * 32);
    }
    __builtin_amdgcn_s_setprio(1);
#pragma unroll
    for (int mi = 0; mi < 4; ++mi)
#pragma unroll
      for (int ni = 0; ni < 4; ++ni)
        acc[mi][ni] = __builtin_amdgcn_mfma_f32_16x16x32_bf16(af[mi], bf[ni], acc[mi][ni], 0, 0, 0);
    __builtin_amdgcn_s_setprio(0);
    __builtin_amdgcn_s_barrier();
    cur = cur == 2 ? 0 : cur + 1;
  }

  const int lq = lane >> 4, lc = lane & 15;
#pragma unroll
  for (int nj = 0; nj < 4; ++nj) {
    const int n_l = wn * 64 + nj * 16 + lc;
    const float bias = b1[e * HID + n0 + n_l];
#pragma unroll
    for (int mi = 0; mi < 4; ++mi) {
#pragma unroll
      for (int j = 0; j < 4; ++j) {
        const int m_l = wm * 64 + mi * 16 + lq * 4 + j;
        float v = acc[mi][nj][j] + bias;
        h[((size_t)(e * CAP + m0 + m_l)) * HID + (n0 + n_l)] = f2bf(gelu_f(v));
      }
    }
  }
}

__global__ __launch_bounds__(512, 4)
void fc2_bf(const u16* __restrict__ h, const u16* __restrict__ w2t,
            const float* __restrict__ b2, const int* __restrict__ tok_idx,
            const float* __restrict__ expw, float* __restrict__ out) {
  const int p = blockIdx.x;
  const int l = (p & 7) * 64 + (p >> 3);         // bijective XCD remap (512 = 8*64)
  const int e  = l >> 3;
  const int mt = (l >> 1) & 3;
  const int nt = l & 1;
  const int m0 = mt * 128, n0 = nt * 256;
  const int t = threadIdx.x;
  const int lane = t & 63, wave = t >> 6;
  const int wm = wave >> 2, wn = wave & 3;

  __shared__ __align__(16) u16 AsmF[3 * A_EL];
  __shared__ __align__(16) u16 BsmF[3 * B_EL];

  const int kc = ((lane & 3) ^ ((lane >> 3) & 3)) * 8;
  const int rloc = lane >> 2;
  const int wOff = wave * 512;

  const int arow = wave * 16 + rloc;
  const u16* aSrc  = h + ((size_t)(e * CAP + m0 + arow)) * HID + kc;
  const u16* bSrc0 = w2t + ((size_t)e * DIM + n0 + arow) * HID + kc;
  const u16* bSrc1 = w2t + ((size_t)e * DIM + n0 + 128 + arow) * HID + kc;

  f32x4 acc[4][4] = {};
  const int lr = lane & 15, hi4 = lane >> 4;

  STG3(0, 0);
  STG3(1, 32);
  int cur = 0;
  const int KT = HID / 32;                       // 32
  for (int tt = 0; tt < KT; ++tt) {
    if (tt < KT - 1) asm volatile("s_waitcnt vmcnt(3)" ::: "memory");
    else             asm volatile("s_waitcnt vmcnt(0)" ::: "memory");
    __builtin_amdgcn_s_barrier();
    const u16* Ab = AsmF + cur * A_EL;
    const u16* Bb = BsmF + cur * B_EL;
    bf16x8 af[4], bf[4];
#pragma unroll
    for (int mi = 0; mi < 4; ++mi) af[mi] = LDSW(Ab, wm * 64 + mi * 16 + lr, hi4);
#pragma unroll
    for (int ni = 0; ni < 4; ++ni) bf[ni] = LDSW(Bb, wn * 64 + ni * 16 + lr, hi4);
    if (tt + 2 < KT) {
      const int bs = (tt + 2) % 3;
      STG3(bs, (tt + 2) * 32);
    }
    __builtin_amdgcn_s_setprio(1);
#pragma unroll
    for (int mi = 0; mi < 4; ++mi)
#pragma unroll
      for (int ni = 0; ni < 4; ++ni)
        acc[mi][ni] = __builtin_amdgcn_mfma_f32_16x16x32_bf16(af[mi], bf[ni], acc[mi][ni], 0, 0, 0);
    __builtin_amdgcn_s_setprio(0);
    __builtin_amdgcn_s_barrier();
    cur = cur == 2 ? 0 : cur + 1;
  }

  const int lq = lane >> 4, lc = lane & 15;
  int   tokm[4][4];
  float wgt[4][4];
#pragma unroll
  for (int mi = 0; mi < 4; ++mi)
#pragma unroll
    for (int j = 0; j < 4; ++j) {
      const int m_l = wm * 64 + mi * 16 + lq * 4 + j;
      tokm[mi][j] = tok_idx[e * CAP + m0 + m_l];
      wgt[mi][j]  = expw[e * CAP + m0 + m_l];
    }
#pragma unroll
  for (int nj = 0; nj < 4; ++nj) {
    const int n_l = wn * 64 + nj * 16 + lc;
    const float bias = b2[e * DIM + n0 + n_l];
#pragma unroll
    for (int mi = 0; mi < 4; ++mi)
#pragma unroll
      for (int j = 0; j < 4; ++j) {
        float v = (acc[mi][nj][j] + bias) * wgt[mi][j];
        atomicAdd(out + (size_t)tokm[mi][j] * DIM + (n0 + n_l), v);
      }
  }
}

// ===================== fallback f32-input GEMMs (ws too small) =====================
#define SWZ(row, cb) ((cb) ^ (((((row) >> 3) ^ (row)) & 7) << 4))

__global__ __launch_bounds__(256)
void fc1_kernel(const float* __restrict__ x, const int* __restrict__ tok_idx,
                const float* __restrict__ w1, const float* __restrict__ b1,
                u16* __restrict__ h) {
  const int bx = blockIdx.x;
  const int e  = bx >> 5;
  const int mt = (bx >> 3) & 3;
  const int nt = bx & 7;
  const int m0 = mt * 128, n0 = nt * 128;
  const int t = threadIdx.x;
  const int lane = t & 63, wave = t >> 6;
  const int wm = wave >> 1, wn = wave & 1;

  __shared__ __align__(16) u16 Asm[128 * 64];
  __shared__ __align__(16) u16 Bsm[128 * 64];

  const int arq = t & 31, akq = t >> 5;
  int tokr[4];
#pragma unroll
  for (int j = 0; j < 4; ++j) tokr[j] = tok_idx[e * CAP + m0 + arq * 4 + j];
  const int nq = t & 31, kq = t >> 5;
  const float* bptr = w1 + (size_t)e * DIM * HID + n0 + nq * 4;

  f32x4 acc[4][4] = {};

  for (int k0 = 0; k0 < DIM; k0 += 64) {
    float4 av0[4], av1[4];
#pragma unroll
    for (int j = 0; j < 4; ++j) {
      const float* ap = x + (size_t)tokr[j] * DIM + k0 + akq * 8;
      av0[j] = *(const float4*)(ap);
      av1[j] = *(const float4*)(ap + 4);
    }
    float4 bv[8];
#pragma unroll
    for (int kk = 0; kk < 8; ++kk)
      bv[kk] = *(const float4*)(bptr + (size_t)(k0 + kq * 8 + kk) * HID);
    __syncthreads();
#pragma unroll
    for (int j = 0; j < 4; ++j) {
      const int row = arq * 4 + j;
      ushort4 w0, w1v;
      w0.x = f2bf(av0[j].x); w0.y = f2bf(av0[j].y); w0.z = f2bf(av0[j].z); w0.w = f2bf(av0[j].w);
      w1v.x = f2bf(av1[j].x); w1v.y = f2bf(av1[j].y); w1v.z = f2bf(av1[j].z); w1v.w = f2bf(av1[j].w);
      *(ushort4*)((char*)Asm + row * 128 + SWZ(row, (akq * 8 + 0) * 2)) = w0;
      *(ushort4*)((char*)Asm + row * 128 + SWZ(row, (akq * 8 + 4) * 2)) = w1v;
    }
#pragma unroll
    for (int g = 0; g < 2; ++g) {
#pragma unroll
      for (int j = 0; j < 4; ++j) {
        ushort4 wv;
        wv.x = f2bf(GET4(bv[g * 4 + 0], j));
        wv.y = f2bf(GET4(bv[g * 4 + 1], j));
        wv.z = f2bf(GET4(bv[g * 4 + 2], j));
        wv.w = f2bf(GET4(bv[g * 4 + 3], j));
        const int row = nq * 4 + j;
        const int cb = (kq * 8 + g * 4) * 2;
        *(ushort4*)((char*)Bsm + row * 128 + SWZ(row, cb)) = wv;
      }
    }
    __syncthreads();
#pragma unroll
    for (int ks = 0; ks < 2; ++ks) {
      bf16x8 af[4], bf[4];
#pragma unroll
      for (int mi = 0; mi < 4; ++mi) {
        const int row = wm * 64 + mi * 16 + (lane & 15);
        const int cb = ks * 64 + (lane >> 4) * 16;
        af[mi] = *(const bf16x8*)((const char*)Asm + row * 128 + SWZ(row, cb));
      }
#pragma unroll
      for (int ni = 0; ni < 4; ++ni) {
        const int row = wn * 64 + ni * 16 + (lane & 15);
        const int cb = ks * 64 + (lane >> 4) * 16;
        bf[ni] = *(const bf16x8*)((const char*)Bsm + row * 128 + SWZ(row, cb));
      }
#pragma unroll
      for (int mi = 0; mi < 4; ++mi)
#pragma unroll
        for (int ni = 0; ni < 4; ++ni)
          acc[mi][ni] = __builtin_amdgcn_mfma_f32_16x16x32_bf16(af[mi], bf[ni], acc[mi][ni], 0, 0, 0);
    }
  }
  const int lq = lane >> 4, lc = lane & 15;
#pragma unroll
  for (int ni = 0; ni < 4; ++ni) {
    const int n_l = wn * 64 + ni * 16 + lc;
    const float bias = b1[e * HID + n0 + n_l];
#pragma unroll
    for (int mi = 0; mi < 4; ++mi) {
#pragma unroll
      for (int j = 0; j < 4; ++j) {
        const int m_l = wm * 64 + mi * 16 + lq * 4 + j;
        float v = acc[mi][ni][j] + bias;
        h[((size_t)(e * CAP + m0 + m_l)) * HID + (n0 + n_l)] = f2bf(gelu_f(v));
      }
    }
  }
}

__global__ __launch_bounds__(256)
void fc2_kernel(const u16* __restrict__ h, const float* __restrict__ w2,
                const float* __restrict__ b2, const int* __restrict__ tok_idx,
                const float* __restrict__ expw, float* __restrict__ out) {
  const int bx = blockIdx.x;
  const int e  = bx >> 4;
  const int mt = (bx >> 2) & 3;
  const int nt = bx & 3;
  const int m0 = mt * 128, n0 = nt * 128;
  const int t = threadIdx.x;
  const int lane = t & 63, wave = t >> 6;
  const int wm = wave >> 1, wn = wave & 1;

  __shared__ __align__(16) u16 Asm[128 * 64];
  __shared__ __align__(16) u16 Bsm[128 * 64];

  const int arq = t & 31, akq = t >> 5;
  const u16* aptr0 = h + ((size_t)(e * CAP + m0 + arq * 4)) * HID + akq * 8;
  const int nq = t & 31, kq = t >> 5;
  const float* bptr = w2 + (size_t)e * HID * DIM + n0 + nq * 4;

  f32x4 acc[4][4] = {};

  for (int k0 = 0; k0 < HID; k0 += 64) {
    uint4 av[4];
#pragma unroll
    for (int j = 0; j < 4; ++j)
      av[j] = *(const uint4*)(aptr0 + (size_t)j * HID + k0);
    float4 bv[8];
#pragma unroll
    for (int kk = 0; kk < 8; ++kk)
      bv[kk] = *(const float4*)(bptr + (size_t)(k0 + kq * 8 + kk) * DIM);
    __syncthreads();
#pragma unroll
    for (int j = 0; j < 4; ++j) {
      const int row = arq * 4 + j;
      *(uint4*)((char*)Asm + row * 128 + SWZ(row, akq * 16)) = av[j];
    }
#pragma unroll
    for (int g = 0; g < 2; ++g) {
#pragma unroll
      for (int j = 0; j < 4; ++j) {
        ushort4 wv;
        wv.x = f2bf(GET4(bv[g * 4 + 0], j));
        wv.y = f2bf(GET4(bv[g * 4 + 1], j));
        wv.z = f2bf(GET4(bv[g * 4 + 2], j));
        wv.w = f2bf(GET4(bv[g * 4 + 3], j));
        const int row = nq * 4 + j;
        const int cb = (kq * 8 + g * 4) * 2;
        *(ushort4*)((char*)Bsm + row * 128 + SWZ(row, cb)) = wv;
      }
    }
    __syncthreads();
#pragma unroll
    for (int ks = 0; ks < 2; ++ks) {
      bf16x8 af[4], bf[4];
#pragma unroll
      for (int mi = 0; mi < 4; ++mi) {
        const int row = wm * 64 + mi * 16 + (lane & 15);
        const int cb = ks * 64 + (lane >> 4) * 16;
        af[mi] = *(const bf16x8*)((const char*)Asm + row * 128 + SWZ(row, cb));
      }
#pragma unroll
      for (int ni = 0; ni < 4; ++ni) {
        const int row = wn * 64 + ni * 16 + (lane & 15);
        const int cb = ks * 64 + (lane >> 4) * 16;
        bf[ni] = *(const bf16x8*)((const char*)Bsm + row * 128 + SWZ(row, cb));
      }
#pragma unroll
      for (int mi = 0; mi < 4; ++mi)
#pragma unroll
        for (int ni = 0; ni < 4; ++ni)
          acc[mi][ni] = __builtin_amdgcn_mfma_f32_16x16x32_bf16(af[mi], bf[ni], acc[mi][ni], 0, 0, 0);
    }
  }
  const int lq = lane >> 4, lc = lane & 15;
  int   tokm[4][4];
  float wgt[4][4];
#pragma unroll
  for (int mi = 0; mi < 4; ++mi)
#pragma unroll
    for (int j = 0; j < 4; ++j) {
      const int m_l = wm * 64 + mi * 16 + lq * 4 + j;
      tokm[mi][j] = tok_idx[e * CAP + m0 + m_l];
      wgt[mi][j]  = expw[e * CAP + m0 + m_l];
    }
#pragma unroll
  for (int ni = 0; ni < 4; ++ni) {
    const int n_l = wn * 64 + ni * 16 + lc;
    const float bias = b2[e * DIM + n0 + n_l];
#pragma unroll
    for (int mi = 0; mi < 4; ++mi)
#pragma unroll
      for (int j = 0; j < 4; ++j) {
        float v = (acc[mi][ni][j] + bias) * wgt[mi][j];
        atomicAdd(out + (size_t)tokm[mi][j] * DIM + (n0 + n_l), v);
      }
  }
}

extern "C" void kernel_launch(void* const* d_in, const int* in_sizes, int n_in,
                              void* d_out, int out_size, void* d_ws, size_t ws_size,
                              hipStream_t stream) {
  const float* x  = (const float*)d_in[0];
  const float* rw = (const float*)d_in[1];
  const float* w1 = (const float*)d_in[2];
  const float* b1 = (const float*)d_in[3];
  const float* w2 = (const float*)d_in[4];
  const float* b2 = (const float*)d_in[5];
  float* out = (float*)d_out;

  char* ws = (char*)d_ws;
  const size_t MB = 1u << 20;
  float* logits = (float*)ws;                                   // [0, 8M)
  int*   toki   = (int*)(ws + 8 * MB);                          // 128 KB
  float* ew     = (float*)(ws + 8 * MB + (128u << 10));         // 128 KB

  const size_t off_xb = 8 * MB + (256u << 10);   // 8.25M
  const size_t off_wt = off_xb + 32 * MB;        // 40.25M
  const size_t off_h  = off_wt + 64 * MB;        // 104.25M
  const size_t need   = off_h + 64 * MB;         // 168.25M
  const bool big = (ws_size >= need);

  // topk meta scratch: inside h region (big) — consumed before fc1 writes h
  const size_t off_meta = big ? off_h : (8 * MB + (256u << 10));
  u32*   ghist = (u32*)(ws + off_meta);                    // 256 KB
  float* psum  = (float*)(ws + off_meta + (256u << 10));   // 4 KB
  u32*   gpos  = (u32*)(ws + off_meta + (260u << 10));
  u32*   gU    = (u32*)(ws + off_meta + (260u << 10) + 256);
  int*   gX    = (int*)(ws + off_meta + (260u << 10) + 512);
  float* gZ    = (float*)(ws + off_meta + (260u << 10) + 768);

  u16* xb = big ? (u16*)(ws + off_xb) : (u16*)0;

  (void)hipMemsetAsync(d_out, 0, (size_t)out_size * sizeof(float), stream);
  (void)hipMemsetAsync(ws + off_meta, 0, 264u << 10, stream);
  router_kernel<<<dim3(512), dim3(256), 0, stream>>>(x, rw, logits, xb);
  topk_hist<<<dim3(16, 64), dim3(256), 0, stream>>>(logits, ghist, psum);
  topk_select<<<dim3(64), dim3(256), 0, stream>>>(logits, ghist, psum, gU, gX, gZ, gpos,
                                                  out + (size_t)N_TOK * DIM);
  topk_emit<<<dim3(16, 64), dim3(256), 0, stream>>>(logits, gU, gX, gZ, gpos, toki, ew);

  if (big) {
    u16* wt  = (u16*)(ws + off_wt);
    u16* h   = (u16*)(ws + off_h);
    transpose_cvt_kernel<<<dim3(16, 8, 64), dim3(256), 0, stream>>>(w1, wt, 512, 1024);
    fc1_bf<<<dim3(1024), dim3(512), 0, stream>>>(xb, toki, wt, b1, h);
    transpose_cvt_kernel<<<dim3(8, 16, 64), dim3(256), 0, stream>>>(w2, wt, 1024, 512);
    fc2_bf<<<dim3(512), dim3(512), 0, stream>>>(h, wt, b2, toki, ew, out);
  } else {
    u16* h = (u16*)(ws + 8 * MB + (512u << 10)); // after meta in fallback layout
    fc1_kernel<<<dim3(2048), dim3(256), 0, stream>>>(x, toki, w1, b1, h);
    fc2_kernel<<<dim3(1024), dim3(256), 0, stream>>>(h, w2, b2, toki, ew, out);
  }
}

// Round 18
// 426.379 us; speedup vs baseline: 1.0161x; 1.0161x over previous
//
#include <hip/hip_runtime.h>
#include <math.h>

#define N_TOK 32768
#define DIM   512
#define NEXP  64
#define HID   1024
#define CAP   512

typedef float  f32x4  __attribute__((ext_vector_type(4)));
typedef short  bf16x8 __attribute__((ext_vector_type(8)));
typedef unsigned short u16;
typedef unsigned int u32;

#define GET4(v, jj) ((jj) == 0 ? (v).x : (jj) == 1 ? (v).y : (jj) == 2 ? (v).z : (v).w)

__device__ __forceinline__ u16 f2bf(float f) {
  unsigned u = __float_as_uint(f);
  u += 0x7FFFu + ((u >> 16) & 1u);   // RNE
  return (u16)(u >> 16);
}
__device__ __forceinline__ unsigned enc_f(float f) {  // monotone f32 -> u32
  unsigned u = __float_as_uint(f);
  return (u & 0x80000000u) ? ~u : (u | 0x80000000u);
}
__device__ __forceinline__ float dec_f(unsigned k) {
  unsigned u = (k & 0x80000000u) ? (k & 0x7FFFFFFFu) : ~k;
  return __uint_as_float(u);
}
// uniform-width monotone bucket (value space, NOT exponent space): v in [-8,8) -> 0..255
__device__ __forceinline__ int bkt_f(float v) {
  int b = (int)fmaf(v, 16.f, 128.f);
  return b < 0 ? 0 : (b > 255 ? 255 : b);
}
__device__ __forceinline__ void gl16(const u16* g, u16* l) {
  __builtin_amdgcn_global_load_lds(
      (const __attribute__((address_space(1))) unsigned int*)g,
      (__attribute__((address_space(3))) unsigned int*)l, 16, 0, 0);
}
// exact-enough erf (A&S 7.1.26, |eps|<=1.5e-7) -> gelu
__device__ __forceinline__ float gelu_f(float v) {
  float x = fabsf(v) * 0.70710678118654752f;
  float tt = 1.0f / (1.0f + 0.3275911f * x);
  float poly = tt * (0.254829592f + tt * (-0.284496736f + tt * (1.421413741f +
               tt * (-1.453152027f + tt * 1.061405429f))));
  float erfabs = 1.0f - poly * __expf(-x * x);
  float erfv = v >= 0.f ? erfabs : -erfabs;
  return 0.5f * v * (1.0f + erfv);
}

// ---------------- router: LDS-tiled fp32 SGEMM, 64 tok x 64 exp per block ----------------
// Also emits xb = bf16(x) as a by-product.
__global__ __launch_bounds__(256)
void router_kernel(const float* __restrict__ x, const float* __restrict__ rw,
                   float* __restrict__ logitsT, u16* __restrict__ xb) {
  __shared__ float As[32][68];   // [k][m]
  __shared__ float Bs[32][68];   // [k][e]
  const int t = threadIdx.x;
  const int n0 = blockIdx.x * 64;
  const int ty = t >> 4, tx = t & 15;
  const int am = t >> 2, akq = (t & 3) * 8;
  const int bk = t >> 3, beq = (t & 7) * 8;
  const float* xrow = x + (size_t)(n0 + am) * DIM + akq;
  u16* xbrow = xb ? (xb + (size_t)(n0 + am) * DIM + akq) : (u16*)0;
  const float* brow = rw + (size_t)bk * NEXP + beq;

  float acc[4][4] = {};
  for (int k0 = 0; k0 < DIM; k0 += 32) {
    float4 a0 = *(const float4*)(xrow + k0);
    float4 a1 = *(const float4*)(xrow + k0 + 4);
    float4 b0 = *(const float4*)(brow + (size_t)k0 * NEXP);
    float4 b1 = *(const float4*)(brow + (size_t)k0 * NEXP + 4);
    if (xbrow) {
      uint4 o;
      o.x = f2bf(a0.x) | ((unsigned)f2bf(a0.y) << 16);
      o.y = f2bf(a0.z) | ((unsigned)f2bf(a0.w) << 16);
      o.z = f2bf(a1.x) | ((unsigned)f2bf(a1.y) << 16);
      o.w = f2bf(a1.z) | ((unsigned)f2bf(a1.w) << 16);
      *(uint4*)(xbrow + k0) = o;
    }
    __syncthreads();
    As[akq + 0][am] = a0.x; As[akq + 1][am] = a0.y;
    As[akq + 2][am] = a0.z; As[akq + 3][am] = a0.w;
    As[akq + 4][am] = a1.x; As[akq + 5][am] = a1.y;
    As[akq + 6][am] = a1.z; As[akq + 7][am] = a1.w;
    *(float4*)&Bs[bk][beq] = b0;
    *(float4*)&Bs[bk][beq + 4] = b1;
    __syncthreads();
#pragma unroll
    for (int k = 0; k < 32; ++k) {
      float4 av = *(const float4*)&As[k][ty * 4];
      float4 bv = *(const float4*)&Bs[k][tx * 4];
#pragma unroll
      for (int i = 0; i < 4; ++i)
#pragma unroll
        for (int j = 0; j < 4; ++j)
          acc[i][j] += GET4(av, i) * GET4(bv, j);
    }
  }
#pragma unroll
  for (int j = 0; j < 4; ++j) {
    float4 o; o.x = acc[0][j]; o.y = acc[1][j]; o.z = acc[2][j]; o.w = acc[3][j];
    *(float4*)(logitsT + (size_t)(tx * 4 + j) * N_TOK + n0 + ty * 4) = o;
  }
}

// ===================== topk pipeline: T1 hist -> T2 select -> T3 emit =====================
// weights = exp(v)/sum(exp(v))  (no max-shift: |v| <= ~4)

// T1: grid (16,64): block (c,e) histograms 2048 tokens into ghist[e][256]; psum[e*16+c]
__global__ __launch_bounds__(256)
void topk_hist(const float* __restrict__ logitsT, u32* __restrict__ ghist,
               float* __restrict__ psum) {
  const int c = blockIdx.x, e = blockIdx.y;
  const int t = threadIdx.x, lane = t & 63, wid = t >> 6;
  __shared__ u32 lh[256];
  __shared__ float wsum[4];
  lh[t] = 0;
  __syncthreads();
  const float* row = logitsT + (size_t)e * N_TOK + c * 2048 + t * 8;
  float4 a = *(const float4*)(row);
  float4 b = *(const float4*)(row + 4);
  float s = 0.f;
#pragma unroll
  for (int j = 0; j < 4; ++j) {
    float v0 = GET4(a, j), v1 = GET4(b, j);
    atomicAdd(&lh[bkt_f(v0)], 1u);
    atomicAdd(&lh[bkt_f(v1)], 1u);
    s += __expf(v0) + __expf(v1);
  }
#pragma unroll
  for (int off = 32; off >= 1; off >>= 1) s += __shfl_xor(s, off);
  if (lane == 0) wsum[wid] = s;
  __syncthreads();
  {
    const u32 hv = lh[t];
    if (hv) atomicAdd(&ghist[e * 256 + t], hv);
  }
  if (t == 0) psum[e * 16 + c] = wsum[0] + wsum[1] + wsum[2] + wsum[3];
}

// T2: 64 blocks (one per expert): find exact ustar + tie bound X; write meta
__global__ __launch_bounds__(256)
void topk_select(const float* __restrict__ logitsT, const u32* __restrict__ ghist,
                 const float* __restrict__ psum, u32* __restrict__ gU,
                 int* __restrict__ gX, float* __restrict__ gZ, u32* __restrict__ gpos,
                 float* __restrict__ auxout) {
  const int e = blockIdx.x;
  const int t = threadIdx.x;
  const float* row = logitsT + (size_t)e * N_TOK;

  __shared__ u32 hist[256];
  __shared__ u32 candK[4096];
  __shared__ int candN[4096];
  __shared__ int tieN[1024];
  __shared__ u32 sh_cnt, sh_rem, sh_chosen, sh_tcnt;
  __shared__ float sh_invZ;

#define SUFFIX_SELECT(NEED) do { \
    if (t < 64) { \
      u32 h0_ = hist[4 * t], h1_ = hist[4 * t + 1], h2_ = hist[4 * t + 2], h3_ = hist[4 * t + 3]; \
      u32 s3_ = h3_, s2_ = h2_ + s3_, s1_ = h1_ + s2_, s0_ = h0_ + s1_; \
      u32 sfx_ = s0_; \
      _Pragma("unroll") for (int off_ = 1; off_ < 64; off_ <<= 1) { \
        u32 o_ = __shfl_down(sfx_, off_); \
        if (t + off_ < 64) sfx_ += o_; } \
      const u32 ex_ = sfx_ - s0_; \
      const u32 S_[4] = {ex_ + s0_, ex_ + s1_, ex_ + s2_, ex_ + s3_}; \
      const u32 Sx_[4] = {ex_ + s1_, ex_ + s2_, ex_ + s3_, ex_}; \
      _Pragma("unroll") for (int k_ = 0; k_ < 4; ++k_) \
        if (S_[k_] >= (NEED) && Sx_[k_] < (NEED)) { sh_chosen = 4 * t + k_; sh_rem = (NEED) - Sx_[k_]; } \
    } \
    __syncthreads(); } while (0)

  if (t == 0) {
    float z = 0.f;
#pragma unroll
    for (int i = 0; i < 16; ++i) z += psum[e * 16 + i];
    sh_invZ = 1.0f / z;
    sh_cnt = 0; sh_tcnt = 0;
  }
  if (t < 256) hist[t] = ghist[e * 256 + t];
  __syncthreads();

  // crossing bucket for rank CAP (counted from the top)
  SUFFIX_SELECT(CAP);
  const u32 b0 = sh_chosen;
  const u32 rem = sh_rem;

  // collect candidates in bucket b0
  for (int i = 0; i < 32; ++i) {
    const int nb = i * 1024 + t * 4;
    float4 v = *(const float4*)(row + nb);
#pragma unroll
    for (int jj = 0; jj < 4; ++jj) {
      const float vv = GET4(v, jj);
      if ((u32)bkt_f(vv) == b0) {
        const u32 p = atomicAdd(&sh_cnt, 1u);
        if (p < 4096u) { candK[p] = enc_f(vv); candN[p] = nb + jj; }
      }
    }
  }
  __syncthreads();
  const u32 cnt = sh_cnt < 4096u ? sh_cnt : 4096u;

  // 4 exact radix passes over enc_f among candidates
  if (t < 256) hist[t] = 0;
  __syncthreads();
  for (u32 i = t; i < cnt; i += 256) atomicAdd(&hist[candK[i] >> 24], 1u);
  __syncthreads();
  SUFFIX_SELECT(rem);
  const u32 dA = sh_chosen, remB = sh_rem;

  if (t < 256) hist[t] = 0;
  __syncthreads();
  for (u32 i = t; i < cnt; i += 256)
    if ((candK[i] >> 24) == dA) atomicAdd(&hist[(candK[i] >> 16) & 0xFFu], 1u);
  __syncthreads();
  SUFFIX_SELECT(remB);
  const u32 dB = sh_chosen, remC = sh_rem;
  const u32 pfxAB = (dA << 8) | dB;

  if (t < 256) hist[t] = 0;
  __syncthreads();
  for (u32 i = t; i < cnt; i += 256)
    if ((candK[i] >> 16) == pfxAB) atomicAdd(&hist[(candK[i] >> 8) & 0xFFu], 1u);
  __syncthreads();
  SUFFIX_SELECT(remC);
  const u32 dC = sh_chosen, remD = sh_rem;
  const u32 pfxABC = (pfxAB << 8) | dC;

  if (t < 256) hist[t] = 0;
  __syncthreads();
  for (u32 i = t; i < cnt; i += 256)
    if ((candK[i] >> 8) == pfxABC) atomicAdd(&hist[candK[i] & 0xFFu], 1u);
  __syncthreads();
  SUFFIX_SELECT(remD);
  const u32 dD = sh_chosen, remF = sh_rem;
  const u32 ustar = (pfxABC << 8) | dD;

  // ties: remF-th smallest token index among candK == ustar
  for (u32 i = t; i < cnt; i += 256)
    if (candK[i] == ustar) {
      const u32 p = atomicAdd(&sh_tcnt, 1u);
      if (p < 1024u) tieN[p] = candN[i];
    }
  __syncthreads();
  if (t == 0) {
    const u32 tcnt = sh_tcnt < 1024u ? sh_tcnt : 1024u;
    int last = -1;
    for (u32 r = 0; r < remF; ++r) {
      int mn = 0x7FFFFFFF;
      for (u32 i = 0; i < tcnt; ++i) {
        const int nn = tieN[i];
        if (nn > last && nn < mn) mn = nn;
      }
      last = mn;
    }
    gU[e] = ustar;
    gX[e] = last;
    gZ[e] = sh_invZ;
    gpos[e] = 0;
    if (e == 0) { auxout[0] = 2.44140625e-4f; auxout[1] = 0.015625f; }
  }
#undef SUFFIX_SELECT
}

// T3: grid (16,64): emit selected tokens
__global__ __launch_bounds__(256)
void topk_emit(const float* __restrict__ logitsT, const u32* __restrict__ gU,
               const int* __restrict__ gX, const float* __restrict__ gZ,
               u32* __restrict__ gpos, int* __restrict__ tok_idx,
               float* __restrict__ expw) {
  const int c = blockIdx.x, e = blockIdx.y;
  const int t = threadIdx.x;
  const u32 us = gU[e];
  const int X = gX[e];
  const float iz = gZ[e];
  const int nb = c * 2048 + t * 8;
  const float* row = logitsT + (size_t)e * N_TOK + nb;
  float4 a = *(const float4*)(row);
  float4 b = *(const float4*)(row + 4);
#pragma unroll
  for (int j = 0; j < 8; ++j) {
    const float v = j < 4 ? GET4(a, j) : GET4(b, j - 4);
    const int n = nb + j;
    const u32 k = enc_f(v);
    if (k > us || (k == us && n <= X)) {
      const u32 p = atomicAdd(&gpos[e], 1u);
      tok_idx[e * CAP + p] = n;
      expw[e * CAP + p] = __expf(v) * iz;
    }
  }
}

// ---------------- prep: per-expert transpose+cvt: f32 [E][R][C] -> bf16 [E][C][R] ----------------
__global__ __launch_bounds__(256)
void transpose_cvt_kernel(const float* __restrict__ in, u16* __restrict__ outp,
                          int R, int C) {
  __shared__ u16 tile[64][66];
  const int e = blockIdx.z;
  const int r0 = blockIdx.y * 64, c0 = blockIdx.x * 64;
  const int t = threadIdx.x;
  {
    const int r = t >> 2, cs = (t & 3) * 16;
    const float* ip = in + ((size_t)e * R + (r0 + r)) * C + c0 + cs;
#pragma unroll
    for (int q = 0; q < 4; ++q) {
      float4 v = *(const float4*)(ip + q * 4);
      tile[r][cs + q * 4 + 0] = f2bf(v.x);
      tile[r][cs + q * 4 + 1] = f2bf(v.y);
      tile[r][cs + q * 4 + 2] = f2bf(v.z);
      tile[r][cs + q * 4 + 3] = f2bf(v.w);
    }
  }
  __syncthreads();
  {
    const int c = t >> 2, rs = (t & 3) * 16;
    u16* op = outp + ((size_t)e * C + (c0 + c)) * R + r0 + rs;
    uint4 o0, o1;
    o0.x = tile[rs + 0][c]  | ((unsigned)tile[rs + 1][c]  << 16);
    o0.y = tile[rs + 2][c]  | ((unsigned)tile[rs + 3][c]  << 16);
    o0.z = tile[rs + 4][c]  | ((unsigned)tile[rs + 5][c]  << 16);
    o0.w = tile[rs + 6][c]  | ((unsigned)tile[rs + 7][c]  << 16);
    o1.x = tile[rs + 8][c]  | ((unsigned)tile[rs + 9][c]  << 16);
    o1.y = tile[rs + 10][c] | ((unsigned)tile[rs + 11][c] << 16);
    o1.z = tile[rs + 12][c] | ((unsigned)tile[rs + 13][c] << 16);
    o1.w = tile[rs + 14][c] | ((unsigned)tile[rs + 15][c] << 16);
    *(uint4*)(op) = o0;
    *(uint4*)(op + 8) = o1;
  }
}

// ===================== bf16 GEMMs: BM128 x BN256, BK=32, 3-buf depth-2, 72KB LDS =====================
#define A_EL 4096      // 128*32 elems (8 KB)
#define B_EL 8192      // 256*32 elems (16 KB)

#define LDSW(base, row, hi4v) \
  (*(const bf16x8*)((const char*)(base) + (row) * 64 + ((((hi4v) ^ (((row) >> 1) & 3))) << 4)))

#define STG3(bs, k0) do { \
  gl16(aSrc + (k0), AsmF + (bs) * A_EL + wOff); \
  gl16(bSrc0 + (k0), BsmF + (bs) * B_EL + wOff); \
  gl16(bSrc1 + (k0), BsmF + (bs) * B_EL + wOff + 4096); \
} while (0)

__global__ __launch_bounds__(512, 4)
void fc1_bf(const u16* __restrict__ xb, const int* __restrict__ tok_idx,
            const u16* __restrict__ w1t, const float* __restrict__ b1,
            u16* __restrict__ h) {
  const int p = blockIdx.x;
  const int l = (p & 7) * 128 + (p >> 3);        // bijective XCD remap (1024 = 8*128)
  const int e  = l >> 4;
  const int mt = (l >> 2) & 3;
  const int nt = l & 3;
  const int m0 = mt * 128, n0 = nt * 256;
  const int t = threadIdx.x;
  const int lane = t & 63, wave = t >> 6;        // 8 waves
  const int wm = wave >> 2, wn = wave & 3;       // 2m x 4n, per-wave C 64x64

  __shared__ __align__(16) u16 AsmF[3 * A_EL];   // 24 KB
  __shared__ __align__(16) u16 BsmF[3 * B_EL];   // 48 KB

  const int kc = ((lane & 3) ^ ((lane >> 3) & 3)) * 8;  // pre-swizzled k elem offset
  const int rloc = lane >> 2;                    // 0..15
  const int wOff = wave * 512;                   // 16 rows x 32 elems

  const int arow = wave * 16 + rloc;             // 0..127
  const int tok = tok_idx[e * CAP + m0 + arow];
  const u16* aSrc  = xb + (size_t)tok * DIM + kc;
  const u16* bSrc0 = w1t + ((size_t)e * HID + n0 + arow) * DIM + kc;
  const u16* bSrc1 = w1t + ((size_t)e * HID + n0 + 128 + arow) * DIM + kc;

  f32x4 acc[4][4] = {};
  const int lr = lane & 15, hi4 = lane >> 4;

  STG3(0, 0);     // K-tile 0 -> buf 0
  STG3(1, 32);    // K-tile 1 -> buf 1
  int cur = 0;
  const int KT = DIM / 32;                       // 16
  for (int tt = 0; tt < KT; ++tt) {
    if (tt < KT - 1) asm volatile("s_waitcnt vmcnt(3)" ::: "memory");
    else             asm volatile("s_waitcnt vmcnt(0)" ::: "memory");
    __builtin_amdgcn_s_barrier();
    const u16* Ab = AsmF + cur * A_EL;
    const u16* Bb = BsmF + cur * B_EL;
    bf16x8 af[4], bf[4];
#pragma unroll
    for (int mi = 0; mi < 4; ++mi) af[mi] = LDSW(Ab, wm * 64 + mi * 16 + lr, hi4);
#pragma unroll
    for (int ni = 0; ni < 4; ++ni) bf[ni] = LDSW(Bb, wn * 64 + ni * 16 + lr, hi4);
    if (tt + 2 < KT) {
      const int bs = (tt + 2) % 3;
      STG3(bs, (tt + 2) * 32);
    }
    __builtin_amdgcn_s_setprio(1);
#pragma unroll
    for (int mi = 0; mi < 4; ++mi)
#pragma unroll
      for (int ni = 0; ni < 4; ++ni)
        acc[mi][ni] = __builtin_amdgcn_mfma_f32_16x16x32_bf16(af[mi], bf[ni], acc[mi][ni], 0, 0, 0);
    __builtin_amdgcn_s_setprio(0);
    __builtin_amdgcn_s_barrier();
    cur = cur == 2 ? 0 : cur + 1;
  }

  const int lq = lane >> 4, lc = lane & 15;
#pragma unroll
  for (int nj = 0; nj < 4; ++nj) {
    const int n_l = wn * 64 + nj * 16 + lc;
    const float bias = b1[e * HID + n0 + n_l];
#pragma unroll
    for (int mi = 0; mi < 4; ++mi) {
#pragma unroll
      for (int j = 0; j < 4; ++j) {
        const int m_l = wm * 64 + mi * 16 + lq * 4 + j;
        float v = acc[mi][nj][j] + bias;
        h[((size_t)(e * CAP + m0 + m_l)) * HID + (n0 + n_l)] = f2bf(gelu_f(v));
      }
    }
  }
}

__global__ __launch_bounds__(512, 4)
void fc2_bf(const u16* __restrict__ h, const u16* __restrict__ w2t,
            const float* __restrict__ b2, const int* __restrict__ tok_idx,
            const float* __restrict__ expw, float* __restrict__ out) {
  const int p = blockIdx.x;
  const int l = (p & 7) * 64 + (p >> 3);         // bijective XCD remap (512 = 8*64)
  const int e  = l >> 3;
  const int mt = (l >> 1) & 3;
  const int nt = l & 1;
  const int m0 = mt * 128, n0 = nt * 256;
  const int t = threadIdx.x;
  const int lane = t & 63, wave = t >> 6;
  const int wm = wave >> 2, wn = wave & 3;

  __shared__ __align__(16) u16 AsmF[3 * A_EL];
  __shared__ __align__(16) u16 BsmF[3 * B_EL];

  const int kc = ((lane & 3) ^ ((lane >> 3) & 3)) * 8;
  const int rloc = lane >> 2;
  const int wOff = wave * 512;

  const int arow = wave * 16 + rloc;
  const u16* aSrc  = h + ((size_t)(e * CAP + m0 + arow)) * HID + kc;
  const u16* bSrc0 = w2t + ((size_t)e * DIM + n0 + arow) * HID + kc;
  const u16* bSrc1 = w2t + ((size_t)e * DIM + n0 + 128 + arow) * HID + kc;

  f32x4 acc[4][4] = {};
  const int lr = lane & 15, hi4 = lane >> 4;

  STG3(0, 0);
  STG3(1, 32);
  int cur = 0;
  const int KT = HID / 32;                       // 32
  for (int tt = 0; tt < KT; ++tt) {
    if (tt < KT - 1) asm volatile("s_waitcnt vmcnt(3)" ::: "memory");
    else             asm volatile("s_waitcnt vmcnt(0)" ::: "memory");
    __builtin_amdgcn_s_barrier();
    const u16* Ab = AsmF + cur * A_EL;
    const u16* Bb = BsmF + cur * B_EL;
    bf16x8 af[4], bf[4];
#pragma unroll
    for (int mi = 0; mi < 4; ++mi) af[mi] = LDSW(Ab, wm * 64 + mi * 16 + lr, hi4);
#pragma unroll
    for (int ni = 0; ni < 4; ++ni) bf[ni] = LDSW(Bb, wn * 64 + ni * 16 + lr, hi4);
    if (tt + 2 < KT) {
      const int bs = (tt + 2) % 3;
      STG3(bs, (tt + 2) * 32);
    }
    __builtin_amdgcn_s_setprio(1);
#pragma unroll
    for (int mi = 0; mi < 4; ++mi)
#pragma unroll
      for (int ni = 0; ni < 4; ++ni)
        acc[mi][ni] = __builtin_amdgcn_mfma_f32_16x16x32_bf16(af[mi], bf[ni], acc[mi][ni], 0, 0, 0);
    __builtin_amdgcn_s_setprio(0);
    __builtin_amdgcn_s_barrier();
    cur = cur == 2 ? 0 : cur + 1;
  }

  const int lq = lane >> 4, lc = lane & 15;
  int   tokm[4][4];
  float wgt[4][4];
#pragma unroll
  for (int mi = 0; mi < 4; ++mi)
#pragma unroll
    for (int j = 0; j < 4; ++j) {
      const int m_l = wm * 64 + mi * 16 + lq * 4 + j;
      tokm[mi][j] = tok_idx[e * CAP + m0 + m_l];
      wgt[mi][j]  = expw[e * CAP + m0 + m_l];
    }
#pragma unroll
  for (int nj = 0; nj < 4; ++nj) {
    const int n_l = wn * 64 + nj * 16 + lc;
    const float bias = b2[e * DIM + n0 + n_l];
#pragma unroll
    for (int mi = 0; mi < 4; ++mi)
#pragma unroll
      for (int j = 0; j < 4; ++j) {
        float v = (acc[mi][nj][j] + bias) * wgt[mi][j];
        atomicAdd(out + (size_t)tokm[mi][j] * DIM + (n0 + n_l), v);
      }
  }
}

// ===================== fallback f32-input GEMMs (ws too small) =====================
#define SWZ(row, cb) ((cb) ^ (((((row) >> 3) ^ (row)) & 7) << 4))

__global__ __launch_bounds__(256)
void fc1_kernel(const float* __restrict__ x, const int* __restrict__ tok_idx,
                const float* __restrict__ w1, const float* __restrict__ b1,
                u16* __restrict__ h) {
  const int bx = blockIdx.x;
  const int e  = bx >> 5;
  const int mt = (bx >> 3) & 3;
  const int nt = bx & 7;
  const int m0 = mt * 128, n0 = nt * 128;
  const int t = threadIdx.x;
  const int lane = t & 63, wave = t >> 6;
  const int wm = wave >> 1, wn = wave & 1;

  __shared__ __align__(16) u16 Asm[128 * 64];
  __shared__ __align__(16) u16 Bsm[128 * 64];

  const int arq = t & 31, akq = t >> 5;
  int tokr[4];
#pragma unroll
  for (int j = 0; j < 4; ++j) tokr[j] = tok_idx[e * CAP + m0 + arq * 4 + j];
  const int nq = t & 31, kq = t >> 5;
  const float* bptr = w1 + (size_t)e * DIM * HID + n0 + nq * 4;

  f32x4 acc[4][4] = {};

  for (int k0 = 0; k0 < DIM; k0 += 64) {
    float4 av0[4], av1[4];
#pragma unroll
    for (int j = 0; j < 4; ++j) {
      const float* ap = x + (size_t)tokr[j] * DIM + k0 + akq * 8;
      av0[j] = *(const float4*)(ap);
      av1[j] = *(const float4*)(ap + 4);
    }
    float4 bv[8];
#pragma unroll
    for (int kk = 0; kk < 8; ++kk)
      bv[kk] = *(const float4*)(bptr + (size_t)(k0 + kq * 8 + kk) * HID);
    __syncthreads();
#pragma unroll
    for (int j = 0; j < 4; ++j) {
      const int row = arq * 4 + j;
      ushort4 w0, w1v;
      w0.x = f2bf(av0[j].x); w0.y = f2bf(av0[j].y); w0.z = f2bf(av0[j].z); w0.w = f2bf(av0[j].w);
      w1v.x = f2bf(av1[j].x); w1v.y = f2bf(av1[j].y); w1v.z = f2bf(av1[j].z); w1v.w = f2bf(av1[j].w);
      *(ushort4*)((char*)Asm + row * 128 + SWZ(row, (akq * 8 + 0) * 2)) = w0;
      *(ushort4*)((char*)Asm + row * 128 + SWZ(row, (akq * 8 + 4) * 2)) = w1v;
    }
#pragma unroll
    for (int g = 0; g < 2; ++g) {
#pragma unroll
      for (int j = 0; j < 4; ++j) {
        ushort4 wv;
        wv.x = f2bf(GET4(bv[g * 4 + 0], j));
        wv.y = f2bf(GET4(bv[g * 4 + 1], j));
        wv.z = f2bf(GET4(bv[g * 4 + 2], j));
        wv.w = f2bf(GET4(bv[g * 4 + 3], j));
        const int row = nq * 4 + j;
        const int cb = (kq * 8 + g * 4) * 2;
        *(ushort4*)((char*)Bsm + row * 128 + SWZ(row, cb)) = wv;
      }
    }
    __syncthreads();
#pragma unroll
    for (int ks = 0; ks < 2; ++ks) {
      bf16x8 af[4], bf[4];
#pragma unroll
      for (int mi = 0; mi < 4; ++mi) {
        const int row = wm * 64 + mi * 16 + (lane & 15);
        const int cb = ks * 64 + (lane >> 4) * 16;
        af[mi] = *(const bf16x8*)((const char*)Asm + row * 128 + SWZ(row, cb));
      }
#pragma unroll
      for (int ni = 0; ni < 4; ++ni) {
        const int row = wn * 64 + ni * 16 + (lane & 15);
        const int cb = ks * 64 + (lane >> 4) * 16;
        bf[ni] = *(const bf16x8*)((const char*)Bsm + row * 128 + SWZ(row, cb));
      }
#pragma unroll
      for (int mi = 0; mi < 4; ++mi)
#pragma unroll
        for (int ni = 0; ni < 4; ++ni)
          acc[mi][ni] = __builtin_amdgcn_mfma_f32_16x16x32_bf16(af[mi], bf[ni], acc[mi][ni], 0, 0, 0);
    }
  }
  const int lq = lane >> 4, lc = lane & 15;
#pragma unroll
  for (int ni = 0; ni < 4; ++ni) {
    const int n_l = wn * 64 + ni * 16 + lc;
    const float bias = b1[e * HID + n0 + n_l];
#pragma unroll
    for (int mi = 0; mi < 4; ++mi) {
#pragma unroll
      for (int j = 0; j < 4; ++j) {
        const int m_l = wm * 64 + mi * 16 + lq * 4 + j;
        float v = acc[mi][ni][j] + bias;
        h[((size_t)(e * CAP + m0 + m_l)) * HID + (n0 + n_l)] = f2bf(gelu_f(v));
      }
    }
  }
}

__global__ __launch_bounds__(256)
void fc2_kernel(const u16* __restrict__ h, const float* __restrict__ w2,
                const float* __restrict__ b2, const int* __restrict__ tok_idx,
                const float* __restrict__ expw, float* __restrict__ out) {
  const int bx = blockIdx.x;
  const int e  = bx >> 4;
  const int mt = (bx >> 2) & 3;
  const int nt = bx & 3;
  const int m0 = mt * 128, n0 = nt * 128;
  const int t = threadIdx.x;
  const int lane = t & 63, wave = t >> 6;
  const int wm = wave >> 1, wn = wave & 1;

  __shared__ __align__(16) u16 Asm[128 * 64];
  __shared__ __align__(16) u16 Bsm[128 * 64];

  const int arq = t & 31, akq = t >> 5;
  const u16* aptr0 = h + ((size_t)(e * CAP + m0 + arq * 4)) * HID + akq * 8;
  const int nq = t & 31, kq = t >> 5;
  const float* bptr = w2 + (size_t)e * HID * DIM + n0 + nq * 4;

  f32x4 acc[4][4] = {};

  for (int k0 = 0; k0 < HID; k0 += 64) {
    uint4 av[4];
#pragma unroll
    for (int j = 0; j < 4; ++j)
      av[j] = *(const uint4*)(aptr0 + (size_t)j * HID + k0);
    float4 bv[8];
#pragma unroll
    for (int kk = 0; kk < 8; ++kk)
      bv[kk] = *(const float4*)(bptr + (size_t)(k0 + kq * 8 + kk) * DIM);
    __syncthreads();
#pragma unroll
    for (int j = 0; j < 4; ++j) {
      const int row = arq * 4 + j;
      *(uint4*)((char*)Asm + row * 128 + SWZ(row, akq * 16)) = av[j];
    }
#pragma unroll
    for (int g = 0; g < 2; ++g) {
#pragma unroll
      for (int j = 0; j < 4; ++j) {
        ushort4 wv;
        wv.x = f2bf(GET4(bv[g * 4 + 0], j));
        wv.y = f2bf(GET4(bv[g * 4 + 1], j));
        wv.z = f2bf(GET4(bv[g * 4 + 2], j));
        wv.w = f2bf(GET4(bv[g * 4 + 3], j));
        const int row = nq * 4 + j;
        const int cb = (kq * 8 + g * 4) * 2;
        *(ushort4*)((char*)Bsm + row * 128 + SWZ(row, cb)) = wv;
      }
    }
    __syncthreads();
#pragma unroll
    for (int ks = 0; ks < 2; ++ks) {
      bf16x8 af[4], bf[4];
#pragma unroll
      for (int mi = 0; mi < 4; ++mi) {
        const int row = wm * 64 + mi * 16 + (lane & 15);
        const int cb = ks * 64 + (lane >> 4) * 16;
        af[mi] = *(const bf16x8*)((const char*)Asm + row * 128 + SWZ(row, cb));
      }
#pragma unroll
      for (int ni = 0; ni < 4; ++ni) {
        const int row = wn * 64 + ni * 16 + (lane & 15);
        const int cb = ks * 64 + (lane >> 4) * 16;
        bf[ni] = *(const bf16x8*)((const char*)Bsm + row * 128 + SWZ(row, cb));
      }
#pragma unroll
      for (int mi = 0; mi < 4; ++mi)
#pragma unroll
        for (int ni = 0; ni < 4; ++ni)
          acc[mi][ni] = __builtin_amdgcn_mfma_f32_16x16x32_bf16(af[mi], bf[ni], acc[mi][ni], 0, 0, 0);
    }
  }
  const int lq = lane >> 4, lc = lane & 15;
  int   tokm[4][4];
  float wgt[4][4];
#pragma unroll
  for (int mi = 0; mi < 4; ++mi)
#pragma unroll
    for (int j = 0; j < 4; ++j) {
      const int m_l = wm * 64 + mi * 16 + lq * 4 + j;
      tokm[mi][j] = tok_idx[e * CAP + m0 + m_l];
      wgt[mi][j]  = expw[e * CAP + m0 + m_l];
    }
#pragma unroll
  for (int ni = 0; ni < 4; ++ni) {
    const int n_l = wn * 64 + ni * 16 + lc;
    const float bias = b2[e * DIM + n0 + n_l];
#pragma unroll
    for (int mi = 0; mi < 4; ++mi)
#pragma unroll
      for (int j = 0; j < 4; ++j) {
        float v = (acc[mi][ni][j] + bias) * wgt[mi][j];
        atomicAdd(out + (size_t)tokm[mi][j] * DIM + (n0 + n_l), v);
      }
  }
}

extern "C" void kernel_launch(void* const* d_in, const int* in_sizes, int n_in,
                              void* d_out, int out_size, void* d_ws, size_t ws_size,
                              hipStream_t stream) {
  const float* x  = (const float*)d_in[0];
  const float* rw = (const float*)d_in[1];
  const float* w1 = (const float*)d_in[2];
  const float* b1 = (const float*)d_in[3];
  const float* w2 = (const float*)d_in[4];
  const float* b2 = (const float*)d_in[5];
  float* out = (float*)d_out;

  char* ws = (char*)d_ws;
  const size_t MB = 1u << 20;
  float* logits = (float*)ws;                                   // [0, 8M)
  int*   toki   = (int*)(ws + 8 * MB);                          // 128 KB
  float* ew     = (float*)(ws + 8 * MB + (128u << 10));         // 128 KB

  const size_t off_xb = 8 * MB + (256u << 10);   // 8.25M
  const size_t off_wt = off_xb + 32 * MB;        // 40.25M
  const size_t off_h  = off_wt + 64 * MB;        // 104.25M
  const size_t need   = off_h + 64 * MB;         // 168.25M
  const bool big = (ws_size >= need);

  // topk meta scratch: inside h region (big) — consumed before fc1 writes h
  const size_t off_meta = big ? off_h : (8 * MB + (256u << 10));
  u32*   ghist = (u32*)(ws + off_meta);                    // 64 KB (64 x 256 x u32)
  float* psum  = (float*)(ws + off_meta + (64u << 10));    // 4 KB
  u32*   gpos  = (u32*)(ws + off_meta + (68u << 10));
  u32*   gU    = (u32*)(ws + off_meta + (68u << 10) + 256);
  int*   gX    = (int*)(ws + off_meta + (68u << 10) + 512);
  float* gZ    = (float*)(ws + off_meta + (68u << 10) + 768);

  u16* xb = big ? (u16*)(ws + off_xb) : (u16*)0;

  (void)hipMemsetAsync(d_out, 0, (size_t)out_size * sizeof(float), stream);
  (void)hipMemsetAsync(ws + off_meta, 0, 69u << 10, stream);
  router_kernel<<<dim3(512), dim3(256), 0, stream>>>(x, rw, logits, xb);
  topk_hist<<<dim3(16, 64), dim3(256), 0, stream>>>(logits, ghist, psum);
  topk_select<<<dim3(64), dim3(256), 0, stream>>>(logits, ghist, psum, gU, gX, gZ, gpos,
                                                  out + (size_t)N_TOK * DIM);
  topk_emit<<<dim3(16, 64), dim3(256), 0, stream>>>(logits, gU, gX, gZ, gpos, toki, ew);

  if (big) {
    u16* wt  = (u16*)(ws + off_wt);
    u16* h   = (u16*)(ws + off_h);
    transpose_cvt_kernel<<<dim3(16, 8, 64), dim3(256), 0, stream>>>(w1, wt, 512, 1024);
    fc1_bf<<<dim3(1024), dim3(512), 0, stream>>>(xb, toki, wt, b1, h);
    transpose_cvt_kernel<<<dim3(8, 16, 64), dim3(256), 0, stream>>>(w2, wt, 1024, 512);
    fc2_bf<<<dim3(512), dim3(512), 0, stream>>>(h, wt, b2, toki, ew, out);
  } else {
    u16* h = (u16*)(ws + 8 * MB + (512u << 10)); // after meta in fallback layout
    fc1_kernel<<<dim3(2048), dim3(256), 0, stream>>>(x, toki, w1, b1, h);
    fc2_kernel<<<dim3(1024), dim3(256), 0, stream>>>(h, w2, b2, toki, ew, out);
  }
}

// Round 19
// 336.585 us; speedup vs baseline: 1.2872x; 1.2668x over previous
//
#include <hip/hip_runtime.h>
#include <math.h>

#define N_TOK 32768
#define DIM   512
#define NEXP  64
#define HID   1024
#define CAP   512

typedef float  f32x4  __attribute__((ext_vector_type(4)));
typedef short  bf16x8 __attribute__((ext_vector_type(8)));
typedef unsigned short u16;
typedef unsigned int u32;

#define GET4(v, jj) ((jj) == 0 ? (v).x : (jj) == 1 ? (v).y : (jj) == 2 ? (v).z : (v).w)

__device__ __forceinline__ u16 f2bf(float f) {
  unsigned u = __float_as_uint(f);
  u += 0x7FFFu + ((u >> 16) & 1u);   // RNE
  return (u16)(u >> 16);
}
__device__ __forceinline__ unsigned enc_f(float f) {  // monotone f32 -> u32
  unsigned u = __float_as_uint(f);
  return (u & 0x80000000u) ? ~u : (u | 0x80000000u);
}
__device__ __forceinline__ float dec_f(unsigned k) {
  unsigned u = (k & 0x80000000u) ? (k & 0x7FFFFFFFu) : ~k;
  return __uint_as_float(u);
}
// uniform-width monotone bucket: v in [-8,8) -> 0..255
__device__ __forceinline__ int bkt_f(float v) {
  int b = (int)fmaf(v, 16.f, 128.f);
  return b < 0 ? 0 : (b > 255 ? 255 : b);
}
__device__ __forceinline__ void gl16(const u16* g, u16* l) {
  __builtin_amdgcn_global_load_lds(
      (const __attribute__((address_space(1))) unsigned int*)g,
      (__attribute__((address_space(3))) unsigned int*)l, 16, 0, 0);
}
// exact-enough erf (A&S 7.1.26, |eps|<=1.5e-7) -> gelu
__device__ __forceinline__ float gelu_f(float v) {
  float x = fabsf(v) * 0.70710678118654752f;
  float tt = 1.0f / (1.0f + 0.3275911f * x);
  float poly = tt * (0.254829592f + tt * (-0.284496736f + tt * (1.421413741f +
               tt * (-1.453152027f + tt * 1.061405429f))));
  float erfabs = 1.0f - poly * __expf(-x * x);
  float erfv = v >= 0.f ? erfabs : -erfabs;
  return 0.5f * v * (1.0f + erfv);
}

// ---------------- router: LDS-tiled fp32 SGEMM, 64 tok x 64 exp per block ----------------
__global__ __launch_bounds__(256)
void router_kernel(const float* __restrict__ x, const float* __restrict__ rw,
                   float* __restrict__ logitsT, u16* __restrict__ xb) {
  __shared__ float As[32][68];   // [k][m]
  __shared__ float Bs[32][68];   // [k][e]
  const int t = threadIdx.x;
  const int n0 = blockIdx.x * 64;
  const int ty = t >> 4, tx = t & 15;
  const int am = t >> 2, akq = (t & 3) * 8;
  const int bk = t >> 3, beq = (t & 7) * 8;
  const float* xrow = x + (size_t)(n0 + am) * DIM + akq;
  u16* xbrow = xb ? (xb + (size_t)(n0 + am) * DIM + akq) : (u16*)0;
  const float* brow = rw + (size_t)bk * NEXP + beq;

  float acc[4][4] = {};
  for (int k0 = 0; k0 < DIM; k0 += 32) {
    float4 a0 = *(const float4*)(xrow + k0);
    float4 a1 = *(const float4*)(xrow + k0 + 4);
    float4 b0 = *(const float4*)(brow + (size_t)k0 * NEXP);
    float4 b1 = *(const float4*)(brow + (size_t)k0 * NEXP + 4);
    if (xbrow) {
      uint4 o;
      o.x = f2bf(a0.x) | ((unsigned)f2bf(a0.y) << 16);
      o.y = f2bf(a0.z) | ((unsigned)f2bf(a0.w) << 16);
      o.z = f2bf(a1.x) | ((unsigned)f2bf(a1.y) << 16);
      o.w = f2bf(a1.z) | ((unsigned)f2bf(a1.w) << 16);
      *(uint4*)(xbrow + k0) = o;
    }
    __syncthreads();
    As[akq + 0][am] = a0.x; As[akq + 1][am] = a0.y;
    As[akq + 2][am] = a0.z; As[akq + 3][am] = a0.w;
    As[akq + 4][am] = a1.x; As[akq + 5][am] = a1.y;
    As[akq + 6][am] = a1.z; As[akq + 7][am] = a1.w;
    *(float4*)&Bs[bk][beq] = b0;
    *(float4*)&Bs[bk][beq + 4] = b1;
    __syncthreads();
#pragma unroll
    for (int k = 0; k < 32; ++k) {
      float4 av = *(const float4*)&As[k][ty * 4];
      float4 bv = *(const float4*)&Bs[k][tx * 4];
#pragma unroll
      for (int i = 0; i < 4; ++i)
#pragma unroll
        for (int j = 0; j < 4; ++j)
          acc[i][j] += GET4(av, i) * GET4(bv, j);
    }
  }
#pragma unroll
  for (int j = 0; j < 4; ++j) {
    float4 o; o.x = acc[0][j]; o.y = acc[1][j]; o.z = acc[2][j]; o.w = acc[3][j];
    *(float4*)(logitsT + (size_t)(tx * 4 + j) * N_TOK + n0 + ty * 4) = o;
  }
}

// ===================== topk: T1 hist -> T2e select+emit (all LDS atomics) =====================
// weights = exp(v)/sum(exp(v))  (no max-shift: |v| <= ~4)

// T1: grid (16,64): block (c,e) histograms 2048 tokens into ghist[e][256]; psum[e*16+c]
__global__ __launch_bounds__(256)
void topk_hist(const float* __restrict__ logitsT, u32* __restrict__ ghist,
               float* __restrict__ psum) {
  const int c = blockIdx.x, e = blockIdx.y;
  const int t = threadIdx.x, lane = t & 63, wid = t >> 6;
  __shared__ u32 lh[256];
  __shared__ float wsum[4];
  lh[t] = 0;
  __syncthreads();
  const float* row = logitsT + (size_t)e * N_TOK + c * 2048 + t * 8;
  float4 a = *(const float4*)(row);
  float4 b = *(const float4*)(row + 4);
  float s = 0.f;
#pragma unroll
  for (int j = 0; j < 4; ++j) {
    float v0 = GET4(a, j), v1 = GET4(b, j);
    atomicAdd(&lh[bkt_f(v0)], 1u);
    atomicAdd(&lh[bkt_f(v1)], 1u);
    s += __expf(v0) + __expf(v1);
  }
#pragma unroll
  for (int off = 32; off >= 1; off >>= 1) s += __shfl_xor(s, off);
  if (lane == 0) wsum[wid] = s;
  __syncthreads();
  {
    const u32 hv = lh[t];
    if (hv) atomicAdd(&ghist[e * 256 + t], hv);
  }
  if (t == 0) psum[e * 16 + c] = wsum[0] + wsum[1] + wsum[2] + wsum[3];
}

// T2e: 64 blocks (one per expert): select threshold AND emit, single row scan
__global__ __launch_bounds__(256)
void topk_selemit(const float* __restrict__ logitsT, const u32* __restrict__ ghist,
                  const float* __restrict__ psum, int* __restrict__ tok_idx,
                  float* __restrict__ expw, float* __restrict__ auxout) {
  const int e = blockIdx.x;
  const int t = threadIdx.x;
  const int lane = t & 63;
  const float* row = logitsT + (size_t)e * N_TOK;

  __shared__ u32 hist[256];
  __shared__ u32 candK[4096];
  __shared__ int candN[4096];
  __shared__ int tieN[1024];
  __shared__ u32 sh_cnt, sh_pos, sh_rem, sh_chosen, sh_tcnt;
  __shared__ int sh_X;
  __shared__ float sh_invZ;

#define SUFFIX_SELECT(NEED) do { \
    if (t < 64) { \
      u32 h0_ = hist[4 * t], h1_ = hist[4 * t + 1], h2_ = hist[4 * t + 2], h3_ = hist[4 * t + 3]; \
      u32 s3_ = h3_, s2_ = h2_ + s3_, s1_ = h1_ + s2_, s0_ = h0_ + s1_; \
      u32 sfx_ = s0_; \
      _Pragma("unroll") for (int off_ = 1; off_ < 64; off_ <<= 1) { \
        u32 o_ = __shfl_down(sfx_, off_); \
        if (t + off_ < 64) sfx_ += o_; } \
      const u32 ex_ = sfx_ - s0_; \
      const u32 S_[4] = {ex_ + s0_, ex_ + s1_, ex_ + s2_, ex_ + s3_}; \
      const u32 Sx_[4] = {ex_ + s1_, ex_ + s2_, ex_ + s3_, ex_}; \
      _Pragma("unroll") for (int k_ = 0; k_ < 4; ++k_) \
        if (S_[k_] >= (NEED) && Sx_[k_] < (NEED)) { sh_chosen = 4 * t + k_; sh_rem = (NEED) - Sx_[k_]; } \
    } \
    __syncthreads(); } while (0)

  // ballot-compacted emit (LDS counter). All lanes of the wave must reach this.
#define EMIT(PRED, NVAL, VVAL) do { \
    const bool em_ = (PRED); \
    const unsigned long long mask_ = __ballot(em_ ? 1 : 0); \
    if (mask_) { \
      const int lead_ = (int)__builtin_ctzll(mask_); \
      u32 base_ = 0; \
      if (lane == lead_) base_ = atomicAdd(&sh_pos, (u32)__builtin_popcountll(mask_)); \
      base_ = __shfl(base_, lead_); \
      if (em_) { \
        const u32 p_ = base_ + (u32)__builtin_popcountll(mask_ & ((1ULL << lane) - 1ULL)); \
        tok_idx[e * CAP + p_] = (NVAL); \
        expw[e * CAP + p_] = __expf(VVAL) * invZ; \
      } \
    } } while (0)

  if (t == 0) {
    float z = 0.f;
#pragma unroll
    for (int i = 0; i < 16; ++i) z += psum[e * 16 + i];
    sh_invZ = 1.0f / z;
    sh_cnt = 0; sh_pos = 0; sh_tcnt = 0;
  }
  if (t < 256) hist[t] = ghist[e * 256 + t];
  __syncthreads();
  const float invZ = sh_invZ;

  // crossing bucket for rank CAP (from the top)
  SUFFIX_SELECT(CAP);
  const u32 b0 = sh_chosen;
  const u32 rem = sh_rem;

  // single row scan: emit high buckets, collect boundary-bucket candidates
  for (int i = 0; i < 32; ++i) {
    const int nb = i * 1024 + t * 4;
    float4 v4 = *(const float4*)(row + nb);
#pragma unroll
    for (int jj = 0; jj < 4; ++jj) {
      const float vv = GET4(v4, jj);
      const int b = bkt_f(vv);
      EMIT(b > (int)b0, nb + jj, vv);
      if ((u32)b == b0) {
        const u32 p = atomicAdd(&sh_cnt, 1u);
        if (p < 4096u) { candK[p] = enc_f(vv); candN[p] = nb + jj; }
      }
    }
  }
  __syncthreads();
  const u32 cnt = sh_cnt < 4096u ? sh_cnt : 4096u;

  // 4 exact radix passes over enc_f among candidates
  if (t < 256) hist[t] = 0;
  __syncthreads();
  for (u32 i = t; i < cnt; i += 256) atomicAdd(&hist[candK[i] >> 24], 1u);
  __syncthreads();
  SUFFIX_SELECT(rem);
  const u32 dA = sh_chosen, remB = sh_rem;

  if (t < 256) hist[t] = 0;
  __syncthreads();
  for (u32 i = t; i < cnt; i += 256)
    if ((candK[i] >> 24) == dA) atomicAdd(&hist[(candK[i] >> 16) & 0xFFu], 1u);
  __syncthreads();
  SUFFIX_SELECT(remB);
  const u32 dB = sh_chosen, remC = sh_rem;
  const u32 pfxAB = (dA << 8) | dB;

  if (t < 256) hist[t] = 0;
  __syncthreads();
  for (u32 i = t; i < cnt; i += 256)
    if ((candK[i] >> 16) == pfxAB) atomicAdd(&hist[(candK[i] >> 8) & 0xFFu], 1u);
  __syncthreads();
  SUFFIX_SELECT(remC);
  const u32 dC = sh_chosen, remD = sh_rem;
  const u32 pfxABC = (pfxAB << 8) | dC;

  if (t < 256) hist[t] = 0;
  __syncthreads();
  for (u32 i = t; i < cnt; i += 256)
    if ((candK[i] >> 8) == pfxABC) atomicAdd(&hist[candK[i] & 0xFFu], 1u);
  __syncthreads();
  SUFFIX_SELECT(remD);
  const u32 dD = sh_chosen, remF = sh_rem;
  const u32 ustar = (pfxABC << 8) | dD;

  // ties: remF-th smallest token index among candK == ustar
  for (u32 i = t; i < cnt; i += 256)
    if (candK[i] == ustar) {
      const u32 p = atomicAdd(&sh_tcnt, 1u);
      if (p < 1024u) tieN[p] = candN[i];
    }
  __syncthreads();
  if (t == 0) {
    const u32 tcnt = sh_tcnt < 1024u ? sh_tcnt : 1024u;
    int last = -1;
    for (u32 r = 0; r < remF; ++r) {
      int mn = 0x7FFFFFFF;
      for (u32 i = 0; i < tcnt; ++i) {
        const int nn = tieN[i];
        if (nn > last && nn < mn) mn = nn;
      }
      last = mn;
    }
    sh_X = last;
    if (e == 0) { auxout[0] = 2.44140625e-4f; auxout[1] = 0.015625f; }
  }
  __syncthreads();
  const int X = sh_X;

  // boundary emit from LDS candidates (tail-padded so ballots stay convergent)
  for (u32 i0 = 0; i0 < cnt; i0 += 256) {
    const u32 i = i0 + t;
    const bool valid = i < cnt;
    const u32 k = valid ? candK[i] : 0u;
    const int n = valid ? candN[i] : 0;
    const bool em = valid && (k > ustar || (k == ustar && n <= X));
    const float vv = dec_f(k);
    EMIT(em, n, vv);
  }
#undef SUFFIX_SELECT
#undef EMIT
}

// ---------------- prep: per-expert transpose+cvt: f32 [E][R][C] -> bf16 [E][C][R] ----------------
__global__ __launch_bounds__(256)
void transpose_cvt_kernel(const float* __restrict__ in, u16* __restrict__ outp,
                          int R, int C) {
  __shared__ u16 tile[64][66];
  const int e = blockIdx.z;
  const int r0 = blockIdx.y * 64, c0 = blockIdx.x * 64;
  const int t = threadIdx.x;
  {
    const int r = t >> 2, cs = (t & 3) * 16;
    const float* ip = in + ((size_t)e * R + (r0 + r)) * C + c0 + cs;
#pragma unroll
    for (int q = 0; q < 4; ++q) {
      float4 v = *(const float4*)(ip + q * 4);
      tile[r][cs + q * 4 + 0] = f2bf(v.x);
      tile[r][cs + q * 4 + 1] = f2bf(v.y);
      tile[r][cs + q * 4 + 2] = f2bf(v.z);
      tile[r][cs + q * 4 + 3] = f2bf(v.w);
    }
  }
  __syncthreads();
  {
    const int c = t >> 2, rs = (t & 3) * 16;
    u16* op = outp + ((size_t)e * C + (c0 + c)) * R + r0 + rs;
    uint4 o0, o1;
    o0.x = tile[rs + 0][c]  | ((unsigned)tile[rs + 1][c]  << 16);
    o0.y = tile[rs + 2][c]  | ((unsigned)tile[rs + 3][c]  << 16);
    o0.z = tile[rs + 4][c]  | ((unsigned)tile[rs + 5][c]  << 16);
    o0.w = tile[rs + 6][c]  | ((unsigned)tile[rs + 7][c]  << 16);
    o1.x = tile[rs + 8][c]  | ((unsigned)tile[rs + 9][c]  << 16);
    o1.y = tile[rs + 10][c] | ((unsigned)tile[rs + 11][c] << 16);
    o1.z = tile[rs + 12][c] | ((unsigned)tile[rs + 13][c] << 16);
    o1.w = tile[rs + 14][c] | ((unsigned)tile[rs + 15][c] << 16);
    *(uint4*)(op) = o0;
    *(uint4*)(op + 8) = o1;
  }
}

// ===================== bf16 GEMMs: BM128 x BN256, BK=32, 3-buf depth-2, 72KB LDS =====================
#define A_EL 4096      // 128*32 elems (8 KB)
#define B_EL 8192      // 256*32 elems (16 KB)

#define LDSW(base, row, hi4v) \
  (*(const bf16x8*)((const char*)(base) + (row) * 64 + ((((hi4v) ^ (((row) >> 1) & 3))) << 4)))

#define STG3(bs, k0) do { \
  gl16(aSrc + (k0), AsmF + (bs) * A_EL + wOff); \
  gl16(bSrc0 + (k0), BsmF + (bs) * B_EL + wOff); \
  gl16(bSrc1 + (k0), BsmF + (bs) * B_EL + wOff + 4096); \
} while (0)

__global__ __launch_bounds__(512, 4)
void fc1_bf(const u16* __restrict__ xb, const int* __restrict__ tok_idx,
            const u16* __restrict__ w1t, const float* __restrict__ b1,
            u16* __restrict__ h) {
  const int p = blockIdx.x;
  const int l = (p & 7) * 128 + (p >> 3);        // bijective XCD remap (1024 = 8*128)
  const int e  = l >> 4;
  const int mt = (l >> 2) & 3;
  const int nt = l & 3;
  const int m0 = mt * 128, n0 = nt * 256;
  const int t = threadIdx.x;
  const int lane = t & 63, wave = t >> 6;        // 8 waves
  const int wm = wave >> 2, wn = wave & 3;       // 2m x 4n, per-wave C 64x64

  __shared__ __align__(16) u16 AsmF[3 * A_EL];   // 24 KB
  __shared__ __align__(16) u16 BsmF[3 * B_EL];   // 48 KB

  const int kc = ((lane & 3) ^ ((lane >> 3) & 3)) * 8;  // pre-swizzled k elem offset
  const int rloc = lane >> 2;                    // 0..15
  const int wOff = wave * 512;                   // 16 rows x 32 elems

  const int arow = wave * 16 + rloc;             // 0..127
  const int tok = tok_idx[e * CAP + m0 + arow];
  const u16* aSrc  = xb + (size_t)tok * DIM + kc;
  const u16* bSrc0 = w1t + ((size_t)e * HID + n0 + arow) * DIM + kc;
  const u16* bSrc1 = w1t + ((size_t)e * HID + n0 + 128 + arow) * DIM + kc;

  f32x4 acc[4][4] = {};
  const int lr = lane & 15, hi4 = lane >> 4;

  STG3(0, 0);     // K-tile 0 -> buf 0
  STG3(1, 32);    // K-tile 1 -> buf 1
  int cur = 0;
  const int KT = DIM / 32;                       // 16
  for (int tt = 0; tt < KT; ++tt) {
    if (tt < KT - 1) asm volatile("s_waitcnt vmcnt(3)" ::: "memory");
    else             asm volatile("s_waitcnt vmcnt(0)" ::: "memory");
    __builtin_amdgcn_s_barrier();
    const u16* Ab = AsmF + cur * A_EL;
    const u16* Bb = BsmF + cur * B_EL;
    bf16x8 af[4], bf[4];
#pragma unroll
    for (int mi = 0; mi < 4; ++mi) af[mi] = LDSW(Ab, wm * 64 + mi * 16 + lr, hi4);
#pragma unroll
    for (int ni = 0; ni < 4; ++ni) bf[ni] = LDSW(Bb, wn * 64 + ni * 16 + lr, hi4);
    if (tt + 2 < KT) {
      const int bs = (tt + 2) % 3;
      STG3(bs, (tt + 2) * 32);
    }
    __builtin_amdgcn_s_setprio(1);
#pragma unroll
    for (int mi = 0; mi < 4; ++mi)
#pragma unroll
      for (int ni = 0; ni < 4; ++ni)
        acc[mi][ni] = __builtin_amdgcn_mfma_f32_16x16x32_bf16(af[mi], bf[ni], acc[mi][ni], 0, 0, 0);
    __builtin_amdgcn_s_setprio(0);
    __builtin_amdgcn_s_barrier();
    cur = cur == 2 ? 0 : cur + 1;
  }

  const int lq = lane >> 4, lc = lane & 15;
#pragma unroll
  for (int nj = 0; nj < 4; ++nj) {
    const int n_l = wn * 64 + nj * 16 + lc;
    const float bias = b1[e * HID + n0 + n_l];
#pragma unroll
    for (int mi = 0; mi < 4; ++mi) {
#pragma unroll
      for (int j = 0; j < 4; ++j) {
        const int m_l = wm * 64 + mi * 16 + lq * 4 + j;
        float v = acc[mi][nj][j] + bias;
        h[((size_t)(e * CAP + m0 + m_l)) * HID + (n0 + n_l)] = f2bf(gelu_f(v));
      }
    }
  }
}

__global__ __launch_bounds__(512, 4)
void fc2_bf(const u16* __restrict__ h, const u16* __restrict__ w2t,
            const float* __restrict__ b2, const int* __restrict__ tok_idx,
            const float* __restrict__ expw, float* __restrict__ out) {
  const int p = blockIdx.x;
  const int l = (p & 7) * 64 + (p >> 3);         // bijective XCD remap (512 = 8*64)
  const int e  = l >> 3;
  const int mt = (l >> 1) & 3;
  const int nt = l & 1;
  const int m0 = mt * 128, n0 = nt * 256;
  const int t = threadIdx.x;
  const int lane = t & 63, wave = t >> 6;
  const int wm = wave >> 2, wn = wave & 3;

  __shared__ __align__(16) u16 AsmF[3 * A_EL];
  __shared__ __align__(16) u16 BsmF[3 * B_EL];

  const int kc = ((lane & 3) ^ ((lane >> 3) & 3)) * 8;
  const int rloc = lane >> 2;
  const int wOff = wave * 512;

  const int arow = wave * 16 + rloc;
  const u16* aSrc  = h + ((size_t)(e * CAP + m0 + arow)) * HID + kc;
  const u16* bSrc0 = w2t + ((size_t)e * DIM + n0 + arow) * HID + kc;
  const u16* bSrc1 = w2t + ((size_t)e * DIM + n0 + 128 + arow) * HID + kc;

  f32x4 acc[4][4] = {};
  const int lr = lane & 15, hi4 = lane >> 4;

  STG3(0, 0);
  STG3(1, 32);
  int cur = 0;
  const int KT = HID / 32;                       // 32
  for (int tt = 0; tt < KT; ++tt) {
    if (tt < KT - 1) asm volatile("s_waitcnt vmcnt(3)" ::: "memory");
    else             asm volatile("s_waitcnt vmcnt(0)" ::: "memory");
    __builtin_amdgcn_s_barrier();
    const u16* Ab = AsmF + cur * A_EL;
    const u16* Bb = BsmF + cur * B_EL;
    bf16x8 af[4], bf[4];
#pragma unroll
    for (int mi = 0; mi < 4; ++mi) af[mi] = LDSW(Ab, wm * 64 + mi * 16 + lr, hi4);
#pragma unroll
    for (int ni = 0; ni < 4; ++ni) bf[ni] = LDSW(Bb, wn * 64 + ni * 16 + lr, hi4);
    if (tt + 2 < KT) {
      const int bs = (tt + 2) % 3;
      STG3(bs, (tt + 2) * 32);
    }
    __builtin_amdgcn_s_setprio(1);
#pragma unroll
    for (int mi = 0; mi < 4; ++mi)
#pragma unroll
      for (int ni = 0; ni < 4; ++ni)
        acc[mi][ni] = __builtin_amdgcn_mfma_f32_16x16x32_bf16(af[mi], bf[ni], acc[mi][ni], 0, 0, 0);
    __builtin_amdgcn_s_setprio(0);
    __builtin_amdgcn_s_barrier();
    cur = cur == 2 ? 0 : cur + 1;
  }

  const int lq = lane >> 4, lc = lane & 15;
  int   tokm[4][4];
  float wgt[4][4];
#pragma unroll
  for (int mi = 0; mi < 4; ++mi)
#pragma unroll
    for (int j = 0; j < 4; ++j) {
      const int m_l = wm * 64 + mi * 16 + lq * 4 + j;
      tokm[mi][j] = tok_idx[e * CAP + m0 + m_l];
      wgt[mi][j]  = expw[e * CAP + m0 + m_l];
    }
#pragma unroll
  for (int nj = 0; nj < 4; ++nj) {
    const int n_l = wn * 64 + nj * 16 + lc;
    const float bias = b2[e * DIM + n0 + n_l];
#pragma unroll
    for (int mi = 0; mi < 4; ++mi)
#pragma unroll
      for (int j = 0; j < 4; ++j) {
        float v = (acc[mi][nj][j] + bias) * wgt[mi][j];
        atomicAdd(out + (size_t)tokm[mi][j] * DIM + (n0 + n_l), v);
      }
  }
}

// ===================== fallback f32-input GEMMs (ws too small) =====================
#define SWZ(row, cb) ((cb) ^ (((((row) >> 3) ^ (row)) & 7) << 4))

__global__ __launch_bounds__(256)
void fc1_kernel(const float* __restrict__ x, const int* __restrict__ tok_idx,
                const float* __restrict__ w1, const float* __restrict__ b1,
                u16* __restrict__ h) {
  const int bx = blockIdx.x;
  const int e  = bx >> 5;
  const int mt = (bx >> 3) & 3;
  const int nt = bx & 7;
  const int m0 = mt * 128, n0 = nt * 128;
  const int t = threadIdx.x;
  const int lane = t & 63, wave = t >> 6;
  const int wm = wave >> 1, wn = wave & 1;

  __shared__ __align__(16) u16 Asm[128 * 64];
  __shared__ __align__(16) u16 Bsm[128 * 64];

  const int arq = t & 31, akq = t >> 5;
  int tokr[4];
#pragma unroll
  for (int j = 0; j < 4; ++j) tokr[j] = tok_idx[e * CAP + m0 + arq * 4 + j];
  const int nq = t & 31, kq = t >> 5;
  const float* bptr = w1 + (size_t)e * DIM * HID + n0 + nq * 4;

  f32x4 acc[4][4] = {};

  for (int k0 = 0; k0 < DIM; k0 += 64) {
    float4 av0[4], av1[4];
#pragma unroll
    for (int j = 0; j < 4; ++j) {
      const float* ap = x + (size_t)tokr[j] * DIM + k0 + akq * 8;
      av0[j] = *(const float4*)(ap);
      av1[j] = *(const float4*)(ap + 4);
    }
    float4 bv[8];
#pragma unroll
    for (int kk = 0; kk < 8; ++kk)
      bv[kk] = *(const float4*)(bptr + (size_t)(k0 + kq * 8 + kk) * HID);
    __syncthreads();
#pragma unroll
    for (int j = 0; j < 4; ++j) {
      const int row = arq * 4 + j;
      ushort4 w0, w1v;
      w0.x = f2bf(av0[j].x); w0.y = f2bf(av0[j].y); w0.z = f2bf(av0[j].z); w0.w = f2bf(av0[j].w);
      w1v.x = f2bf(av1[j].x); w1v.y = f2bf(av1[j].y); w1v.z = f2bf(av1[j].z); w1v.w = f2bf(av1[j].w);
      *(ushort4*)((char*)Asm + row * 128 + SWZ(row, (akq * 8 + 0) * 2)) = w0;
      *(ushort4*)((char*)Asm + row * 128 + SWZ(row, (akq * 8 + 4) * 2)) = w1v;
    }
#pragma unroll
    for (int g = 0; g < 2; ++g) {
#pragma unroll
      for (int j = 0; j < 4; ++j) {
        ushort4 wv;
        wv.x = f2bf(GET4(bv[g * 4 + 0], j));
        wv.y = f2bf(GET4(bv[g * 4 + 1], j));
        wv.z = f2bf(GET4(bv[g * 4 + 2], j));
        wv.w = f2bf(GET4(bv[g * 4 + 3], j));
        const int row = nq * 4 + j;
        const int cb = (kq * 8 + g * 4) * 2;
        *(ushort4*)((char*)Bsm + row * 128 + SWZ(row, cb)) = wv;
      }
    }
    __syncthreads();
#pragma unroll
    for (int ks = 0; ks < 2; ++ks) {
      bf16x8 af[4], bf[4];
#pragma unroll
      for (int mi = 0; mi < 4; ++mi) {
        const int row = wm * 64 + mi * 16 + (lane & 15);
        const int cb = ks * 64 + (lane >> 4) * 16;
        af[mi] = *(const bf16x8*)((const char*)Asm + row * 128 + SWZ(row, cb));
      }
#pragma unroll
      for (int ni = 0; ni < 4; ++ni) {
        const int row = wn * 64 + ni * 16 + (lane & 15);
        const int cb = ks * 64 + (lane >> 4) * 16;
        bf[ni] = *(const bf16x8*)((const char*)Bsm + row * 128 + SWZ(row, cb));
      }
#pragma unroll
      for (int mi = 0; mi < 4; ++mi)
#pragma unroll
        for (int ni = 0; ni < 4; ++ni)
          acc[mi][ni] = __builtin_amdgcn_mfma_f32_16x16x32_bf16(af[mi], bf[ni], acc[mi][ni], 0, 0, 0);
    }
  }
  const int lq = lane >> 4, lc = lane & 15;
#pragma unroll
  for (int ni = 0; ni < 4; ++ni) {
    const int n_l = wn * 64 + ni * 16 + lc;
    const float bias = b1[e * HID + n0 + n_l];
#pragma unroll
    for (int mi = 0; mi < 4; ++mi) {
#pragma unroll
      for (int j = 0; j < 4; ++j) {
        const int m_l = wm * 64 + mi * 16 + lq * 4 + j;
        float v = acc[mi][ni][j] + bias;
        h[((size_t)(e * CAP + m0 + m_l)) * HID + (n0 + n_l)] = f2bf(gelu_f(v));
      }
    }
  }
}

__global__ __launch_bounds__(256)
void fc2_kernel(const u16* __restrict__ h, const float* __restrict__ w2,
                const float* __restrict__ b2, const int* __restrict__ tok_idx,
                const float* __restrict__ expw, float* __restrict__ out) {
  const int bx = blockIdx.x;
  const int e  = bx >> 4;
  const int mt = (bx >> 2) & 3;
  const int nt = bx & 3;
  const int m0 = mt * 128, n0 = nt * 128;
  const int t = threadIdx.x;
  const int lane = t & 63, wave = t >> 6;
  const int wm = wave >> 1, wn = wave & 1;

  __shared__ __align__(16) u16 Asm[128 * 64];
  __shared__ __align__(16) u16 Bsm[128 * 64];

  const int arq = t & 31, akq = t >> 5;
  const u16* aptr0 = h + ((size_t)(e * CAP + m0 + arq * 4)) * HID + akq * 8;
  const int nq = t & 31, kq = t >> 5;
  const float* bptr = w2 + (size_t)e * HID * DIM + n0 + nq * 4;

  f32x4 acc[4][4] = {};

  for (int k0 = 0; k0 < HID; k0 += 64) {
    uint4 av[4];
#pragma unroll
    for (int j = 0; j < 4; ++j)
      av[j] = *(const uint4*)(aptr0 + (size_t)j * HID + k0);
    float4 bv[8];
#pragma unroll
    for (int kk = 0; kk < 8; ++kk)
      bv[kk] = *(const float4*)(bptr + (size_t)(k0 + kq * 8 + kk) * DIM);
    __syncthreads();
#pragma unroll
    for (int j = 0; j < 4; ++j) {
      const int row = arq * 4 + j;
      *(uint4*)((char*)Asm + row * 128 + SWZ(row, akq * 16)) = av[j];
    }
#pragma unroll
    for (int g = 0; g < 2; ++g) {
#pragma unroll
      for (int j = 0; j < 4; ++j) {
        ushort4 wv;
        wv.x = f2bf(GET4(bv[g * 4 + 0], j));
        wv.y = f2bf(GET4(bv[g * 4 + 1], j));
        wv.z = f2bf(GET4(bv[g * 4 + 2], j));
        wv.w = f2bf(GET4(bv[g * 4 + 3], j));
        const int row = nq * 4 + j;
        const int cb = (kq * 8 + g * 4) * 2;
        *(ushort4*)((char*)Bsm + row * 128 + SWZ(row, cb)) = wv;
      }
    }
    __syncthreads();
#pragma unroll
    for (int ks = 0; ks < 2; ++ks) {
      bf16x8 af[4], bf[4];
#pragma unroll
      for (int mi = 0; mi < 4; ++mi) {
        const int row = wm * 64 + mi * 16 + (lane & 15);
        const int cb = ks * 64 + (lane >> 4) * 16;
        af[mi] = *(const bf16x8*)((const char*)Asm + row * 128 + SWZ(row, cb));
      }
#pragma unroll
      for (int ni = 0; ni < 4; ++ni) {
        const int row = wn * 64 + ni * 16 + (lane & 15);
        const int cb = ks * 64 + (lane >> 4) * 16;
        bf[ni] = *(const bf16x8*)((const char*)Bsm + row * 128 + SWZ(row, cb));
      }
#pragma unroll
      for (int mi = 0; mi < 4; ++mi)
#pragma unroll
        for (int ni = 0; ni < 4; ++ni)
          acc[mi][ni] = __builtin_amdgcn_mfma_f32_16x16x32_bf16(af[mi], bf[ni], acc[mi][ni], 0, 0, 0);
    }
  }
  const int lq = lane >> 4, lc = lane & 15;
  int   tokm[4][4];
  float wgt[4][4];
#pragma unroll
  for (int mi = 0; mi < 4; ++mi)
#pragma unroll
    for (int j = 0; j < 4; ++j) {
      const int m_l = wm * 64 + mi * 16 + lq * 4 + j;
      tokm[mi][j] = tok_idx[e * CAP + m0 + m_l];
      wgt[mi][j]  = expw[e * CAP + m0 + m_l];
    }
#pragma unroll
  for (int ni = 0; ni < 4; ++ni) {
    const int n_l = wn * 64 + ni * 16 + lc;
    const float bias = b2[e * DIM + n0 + n_l];
#pragma unroll
    for (int mi = 0; mi < 4; ++mi)
#pragma unroll
      for (int j = 0; j < 4; ++j) {
        float v = (acc[mi][ni][j] + bias) * wgt[mi][j];
        atomicAdd(out + (size_t)tokm[mi][j] * DIM + (n0 + n_l), v);
      }
  }
}

extern "C" void kernel_launch(void* const* d_in, const int* in_sizes, int n_in,
                              void* d_out, int out_size, void* d_ws, size_t ws_size,
                              hipStream_t stream) {
  const float* x  = (const float*)d_in[0];
  const float* rw = (const float*)d_in[1];
  const float* w1 = (const float*)d_in[2];
  const float* b1 = (const float*)d_in[3];
  const float* w2 = (const float*)d_in[4];
  const float* b2 = (const float*)d_in[5];
  float* out = (float*)d_out;

  char* ws = (char*)d_ws;
  const size_t MB = 1u << 20;
  float* logits = (float*)ws;                                   // [0, 8M)
  int*   toki   = (int*)(ws + 8 * MB);                          // 128 KB
  float* ew     = (float*)(ws + 8 * MB + (128u << 10));         // 128 KB

  const size_t off_xb = 8 * MB + (256u << 10);   // 8.25M
  const size_t off_wt = off_xb + 32 * MB;        // 40.25M
  const size_t off_h  = off_wt + 64 * MB;        // 104.25M
  const size_t need   = off_h + 64 * MB;         // 168.25M
  const bool big = (ws_size >= need);

  // topk scratch: ghist(64KB) + psum(4KB); lives in h region (consumed before fc1 writes h)
  const size_t off_meta = big ? off_h : (8 * MB + (256u << 10));
  u32*   ghist = (u32*)(ws + off_meta);                    // 64 KB (64 x 256 x u32)
  float* psum  = (float*)(ws + off_meta + (64u << 10));    // 4 KB

  u16* xb = big ? (u16*)(ws + off_xb) : (u16*)0;

  (void)hipMemsetAsync(d_out, 0, (size_t)out_size * sizeof(float), stream);
  (void)hipMemsetAsync(ws + off_meta, 0, 68u << 10, stream);
  router_kernel<<<dim3(512), dim3(256), 0, stream>>>(x, rw, logits, xb);
  topk_hist<<<dim3(16, 64), dim3(256), 0, stream>>>(logits, ghist, psum);
  topk_selemit<<<dim3(64), dim3(256), 0, stream>>>(logits, ghist, psum, toki, ew,
                                                   out + (size_t)N_TOK * DIM);

  if (big) {
    u16* wt  = (u16*)(ws + off_wt);
    u16* h   = (u16*)(ws + off_h);
    transpose_cvt_kernel<<<dim3(16, 8, 64), dim3(256), 0, stream>>>(w1, wt, 512, 1024);
    fc1_bf<<<dim3(1024), dim3(512), 0, stream>>>(xb, toki, wt, b1, h);
    transpose_cvt_kernel<<<dim3(8, 16, 64), dim3(256), 0, stream>>>(w2, wt, 1024, 512);
    fc2_bf<<<dim3(512), dim3(512), 0, stream>>>(h, wt, b2, toki, ew, out);
  } else {
    u16* h = (u16*)(ws + 8 * MB + (512u << 10)); // after meta in fallback layout
    fc1_kernel<<<dim3(2048), dim3(256), 0, stream>>>(x, toki, w1, b1, h);
    fc2_kernel<<<dim3(1024), dim3(256), 0, stream>>>(h, w2, b2, toki, ew, out);
  }
}

// Round 20
// 329.500 us; speedup vs baseline: 1.3149x; 1.0215x over previous
//
#include <hip/hip_runtime.h>
#include <math.h>

#define N_TOK 32768
#define DIM   512
#define NEXP  64
#define HID   1024
#define CAP   512

typedef float  f32x4  __attribute__((ext_vector_type(4)));
typedef short  bf16x8 __attribute__((ext_vector_type(8)));
typedef unsigned short u16;
typedef unsigned int u32;

#define GET4(v, jj) ((jj) == 0 ? (v).x : (jj) == 1 ? (v).y : (jj) == 2 ? (v).z : (v).w)

__device__ __forceinline__ u16 f2bf(float f) {
  unsigned u = __float_as_uint(f);
  u += 0x7FFFu + ((u >> 16) & 1u);   // RNE
  return (u16)(u >> 16);
}
__device__ __forceinline__ unsigned enc_f(float f) {  // monotone f32 -> u32
  unsigned u = __float_as_uint(f);
  return (u & 0x80000000u) ? ~u : (u | 0x80000000u);
}
__device__ __forceinline__ float dec_f(unsigned k) {
  unsigned u = (k & 0x80000000u) ? (k & 0x7FFFFFFFu) : ~k;
  return __uint_as_float(u);
}
// uniform-width monotone bucket: v in [-8,8) -> 0..255
__device__ __forceinline__ int bkt_f(float v) {
  int b = (int)fmaf(v, 16.f, 128.f);
  return b < 0 ? 0 : (b > 255 ? 255 : b);
}
__device__ __forceinline__ void gl16(const u16* g, u16* l) {
  __builtin_amdgcn_global_load_lds(
      (const __attribute__((address_space(1))) unsigned int*)g,
      (__attribute__((address_space(3))) unsigned int*)l, 16, 0, 0);
}
// exact-enough erf (A&S 7.1.26, |eps|<=1.5e-7) -> gelu
__device__ __forceinline__ float gelu_f(float v) {
  float x = fabsf(v) * 0.70710678118654752f;
  float tt = 1.0f / (1.0f + 0.3275911f * x);
  float poly = tt * (0.254829592f + tt * (-0.284496736f + tt * (1.421413741f +
               tt * (-1.453152027f + tt * 1.061405429f))));
  float erfabs = 1.0f - poly * __expf(-x * x);
  float erfv = v >= 0.f ? erfabs : -erfabs;
  return 0.5f * v * (1.0f + erfv);
}

// ---------------- router: LDS-tiled fp32 SGEMM, 64 tok x 64 exp per block ----------------
__global__ __launch_bounds__(256)
void router_kernel(const float* __restrict__ x, const float* __restrict__ rw,
                   float* __restrict__ logitsT, u16* __restrict__ xb) {
  __shared__ float As[32][68];   // [k][m]
  __shared__ float Bs[32][68];   // [k][e]
  const int t = threadIdx.x;
  const int n0 = blockIdx.x * 64;
  const int ty = t >> 4, tx = t & 15;
  const int am = t >> 2, akq = (t & 3) * 8;
  const int bk = t >> 3, beq = (t & 7) * 8;
  const float* xrow = x + (size_t)(n0 + am) * DIM + akq;
  u16* xbrow = xb ? (xb + (size_t)(n0 + am) * DIM + akq) : (u16*)0;
  const float* brow = rw + (size_t)bk * NEXP + beq;

  float acc[4][4] = {};
  for (int k0 = 0; k0 < DIM; k0 += 32) {
    float4 a0 = *(const float4*)(xrow + k0);
    float4 a1 = *(const float4*)(xrow + k0 + 4);
    float4 b0 = *(const float4*)(brow + (size_t)k0 * NEXP);
    float4 b1 = *(const float4*)(brow + (size_t)k0 * NEXP + 4);
    if (xbrow) {
      uint4 o;
      o.x = f2bf(a0.x) | ((unsigned)f2bf(a0.y) << 16);
      o.y = f2bf(a0.z) | ((unsigned)f2bf(a0.w) << 16);
      o.z = f2bf(a1.x) | ((unsigned)f2bf(a1.y) << 16);
      o.w = f2bf(a1.z) | ((unsigned)f2bf(a1.w) << 16);
      *(uint4*)(xbrow + k0) = o;
    }
    __syncthreads();
    As[akq + 0][am] = a0.x; As[akq + 1][am] = a0.y;
    As[akq + 2][am] = a0.z; As[akq + 3][am] = a0.w;
    As[akq + 4][am] = a1.x; As[akq + 5][am] = a1.y;
    As[akq + 6][am] = a1.z; As[akq + 7][am] = a1.w;
    *(float4*)&Bs[bk][beq] = b0;
    *(float4*)&Bs[bk][beq + 4] = b1;
    __syncthreads();
#pragma unroll
    for (int k = 0; k < 32; ++k) {
      float4 av = *(const float4*)&As[k][ty * 4];
      float4 bv = *(const float4*)&Bs[k][tx * 4];
#pragma unroll
      for (int i = 0; i < 4; ++i)
#pragma unroll
        for (int j = 0; j < 4; ++j)
          acc[i][j] += GET4(av, i) * GET4(bv, j);
    }
  }
#pragma unroll
  for (int j = 0; j < 4; ++j) {
    float4 o; o.x = acc[0][j]; o.y = acc[1][j]; o.z = acc[2][j]; o.w = acc[3][j];
    *(float4*)(logitsT + (size_t)(tx * 4 + j) * N_TOK + n0 + ty * 4) = o;
  }
}

// ===================== topk: T1 hist -> T2e select+emit (all LDS atomics) =====================
// weights = exp(v)/sum(exp(v))  (no max-shift: |v| <= ~4)

// T1: grid (16,64): block (c,e) histograms 2048 tokens into ghist[e][256]; psum[e*16+c]
__global__ __launch_bounds__(256)
void topk_hist(const float* __restrict__ logitsT, u32* __restrict__ ghist,
               float* __restrict__ psum) {
  const int c = blockIdx.x, e = blockIdx.y;
  const int t = threadIdx.x, lane = t & 63, wid = t >> 6;
  __shared__ u32 lh[256];
  __shared__ float wsum[4];
  lh[t] = 0;
  __syncthreads();
  const float* row = logitsT + (size_t)e * N_TOK + c * 2048 + t * 8;
  float4 a = *(const float4*)(row);
  float4 b = *(const float4*)(row + 4);
  float s = 0.f;
#pragma unroll
  for (int j = 0; j < 4; ++j) {
    float v0 = GET4(a, j), v1 = GET4(b, j);
    atomicAdd(&lh[bkt_f(v0)], 1u);
    atomicAdd(&lh[bkt_f(v1)], 1u);
    s += __expf(v0) + __expf(v1);
  }
#pragma unroll
  for (int off = 32; off >= 1; off >>= 1) s += __shfl_xor(s, off);
  if (lane == 0) wsum[wid] = s;
  __syncthreads();
  {
    const u32 hv = lh[t];
    if (hv) atomicAdd(&ghist[e * 256 + t], hv);
  }
  if (t == 0) psum[e * 16 + c] = wsum[0] + wsum[1] + wsum[2] + wsum[3];
}

// T2e: 64 blocks (one per expert): select threshold AND emit, single row scan
__global__ __launch_bounds__(256)
void topk_selemit(const float* __restrict__ logitsT, const u32* __restrict__ ghist,
                  const float* __restrict__ psum, int* __restrict__ tok_idx,
                  float* __restrict__ expw, float* __restrict__ auxout) {
  const int e = blockIdx.x;
  const int t = threadIdx.x;
  const int lane = t & 63;
  const float* row = logitsT + (size_t)e * N_TOK;

  __shared__ u32 hist[256];
  __shared__ u32 candK[4096];
  __shared__ int candN[4096];
  __shared__ int tieN[1024];
  __shared__ u32 sh_cnt, sh_pos, sh_rem, sh_chosen, sh_tcnt;
  __shared__ int sh_X;
  __shared__ float sh_invZ;

#define SUFFIX_SELECT(NEED) do { \
    if (t < 64) { \
      u32 h0_ = hist[4 * t], h1_ = hist[4 * t + 1], h2_ = hist[4 * t + 2], h3_ = hist[4 * t + 3]; \
      u32 s3_ = h3_, s2_ = h2_ + s3_, s1_ = h1_ + s2_, s0_ = h0_ + s1_; \
      u32 sfx_ = s0_; \
      _Pragma("unroll") for (int off_ = 1; off_ < 64; off_ <<= 1) { \
        u32 o_ = __shfl_down(sfx_, off_); \
        if (t + off_ < 64) sfx_ += o_; } \
      const u32 ex_ = sfx_ - s0_; \
      const u32 S_[4] = {ex_ + s0_, ex_ + s1_, ex_ + s2_, ex_ + s3_}; \
      const u32 Sx_[4] = {ex_ + s1_, ex_ + s2_, ex_ + s3_, ex_}; \
      _Pragma("unroll") for (int k_ = 0; k_ < 4; ++k_) \
        if (S_[k_] >= (NEED) && Sx_[k_] < (NEED)) { sh_chosen = 4 * t + k_; sh_rem = (NEED) - Sx_[k_]; } \
    } \
    __syncthreads(); } while (0)

#define EMIT(PRED, NVAL, VVAL) do { \
    const bool em_ = (PRED); \
    const unsigned long long mask_ = __ballot(em_ ? 1 : 0); \
    if (mask_) { \
      const int lead_ = (int)__builtin_ctzll(mask_); \
      u32 base_ = 0; \
      if (lane == lead_) base_ = atomicAdd(&sh_pos, (u32)__builtin_popcountll(mask_)); \
      base_ = __shfl(base_, lead_); \
      if (em_) { \
        const u32 p_ = base_ + (u32)__builtin_popcountll(mask_ & ((1ULL << lane) - 1ULL)); \
        tok_idx[e * CAP + p_] = (NVAL); \
        expw[e * CAP + p_] = __expf(VVAL) * invZ; \
      } \
    } } while (0)

  if (t == 0) {
    float z = 0.f;
#pragma unroll
    for (int i = 0; i < 16; ++i) z += psum[e * 16 + i];
    sh_invZ = 1.0f / z;
    sh_cnt = 0; sh_pos = 0; sh_tcnt = 0;
  }
  if (t < 256) hist[t] = ghist[e * 256 + t];
  __syncthreads();
  const float invZ = sh_invZ;

  // crossing bucket for rank CAP (from the top)
  SUFFIX_SELECT(CAP);
  const u32 b0 = sh_chosen;
  const u32 rem = sh_rem;

  // single row scan: emit high buckets, collect boundary-bucket candidates
  for (int i = 0; i < 32; ++i) {
    const int nb = i * 1024 + t * 4;
    float4 v4 = *(const float4*)(row + nb);
#pragma unroll
    for (int jj = 0; jj < 4; ++jj) {
      const float vv = GET4(v4, jj);
      const int b = bkt_f(vv);
      EMIT(b > (int)b0, nb + jj, vv);
      if ((u32)b == b0) {
        const u32 p = atomicAdd(&sh_cnt, 1u);
        if (p < 4096u) { candK[p] = enc_f(vv); candN[p] = nb + jj; }
      }
    }
  }
  __syncthreads();
  const u32 cnt = sh_cnt < 4096u ? sh_cnt : 4096u;

  // 4 exact radix passes over enc_f among candidates
  if (t < 256) hist[t] = 0;
  __syncthreads();
  for (u32 i = t; i < cnt; i += 256) atomicAdd(&hist[candK[i] >> 24], 1u);
  __syncthreads();
  SUFFIX_SELECT(rem);
  const u32 dA = sh_chosen, remB = sh_rem;

  if (t < 256) hist[t] = 0;
  __syncthreads();
  for (u32 i = t; i < cnt; i += 256)
    if ((candK[i] >> 24) == dA) atomicAdd(&hist[(candK[i] >> 16) & 0xFFu], 1u);
  __syncthreads();
  SUFFIX_SELECT(remB);
  const u32 dB = sh_chosen, remC = sh_rem;
  const u32 pfxAB = (dA << 8) | dB;

  if (t < 256) hist[t] = 0;
  __syncthreads();
  for (u32 i = t; i < cnt; i += 256)
    if ((candK[i] >> 16) == pfxAB) atomicAdd(&hist[(candK[i] >> 8) & 0xFFu], 1u);
  __syncthreads();
  SUFFIX_SELECT(remC);
  const u32 dC = sh_chosen, remD = sh_rem;
  const u32 pfxABC = (pfxAB << 8) | dC;

  if (t < 256) hist[t] = 0;
  __syncthreads();
  for (u32 i = t; i < cnt; i += 256)
    if ((candK[i] >> 8) == pfxABC) atomicAdd(&hist[candK[i] & 0xFFu], 1u);
  __syncthreads();
  SUFFIX_SELECT(remD);
  const u32 dD = sh_chosen, remF = sh_rem;
  const u32 ustar = (pfxABC << 8) | dD;

  // ties: remF-th smallest token index among candK == ustar
  for (u32 i = t; i < cnt; i += 256)
    if (candK[i] == ustar) {
      const u32 p = atomicAdd(&sh_tcnt, 1u);
      if (p < 1024u) tieN[p] = candN[i];
    }
  __syncthreads();
  if (t == 0) {
    const u32 tcnt = sh_tcnt < 1024u ? sh_tcnt : 1024u;
    int last = -1;
    for (u32 r = 0; r < remF; ++r) {
      int mn = 0x7FFFFFFF;
      for (u32 i = 0; i < tcnt; ++i) {
        const int nn = tieN[i];
        if (nn > last && nn < mn) mn = nn;
      }
      last = mn;
    }
    sh_X = last;
    if (e == 0) { auxout[0] = 2.44140625e-4f; auxout[1] = 0.015625f; }
  }
  __syncthreads();
  const int X = sh_X;

  // boundary emit from LDS candidates (tail-padded so ballots stay convergent)
  for (u32 i0 = 0; i0 < cnt; i0 += 256) {
    const u32 i = i0 + t;
    const bool valid = i < cnt;
    const u32 k = valid ? candK[i] : 0u;
    const int n = valid ? candN[i] : 0;
    const bool em = valid && (k > ustar || (k == ustar && n <= X));
    const float vv = dec_f(k);
    EMIT(em, n, vv);
  }
#undef SUFFIX_SELECT
#undef EMIT
}

// ---------------- prep: per-expert transpose+cvt: f32 [E][R][C] -> bf16 [E][C][R] ----------------
__global__ __launch_bounds__(256)
void transpose_cvt_kernel(const float* __restrict__ in, u16* __restrict__ outp,
                          int R, int C) {
  __shared__ u16 tile[64][66];
  const int e = blockIdx.z;
  const int r0 = blockIdx.y * 64, c0 = blockIdx.x * 64;
  const int t = threadIdx.x;
  {
    const int r = t >> 2, cs = (t & 3) * 16;
    const float* ip = in + ((size_t)e * R + (r0 + r)) * C + c0 + cs;
#pragma unroll
    for (int q = 0; q < 4; ++q) {
      float4 v = *(const float4*)(ip + q * 4);
      tile[r][cs + q * 4 + 0] = f2bf(v.x);
      tile[r][cs + q * 4 + 1] = f2bf(v.y);
      tile[r][cs + q * 4 + 2] = f2bf(v.z);
      tile[r][cs + q * 4 + 3] = f2bf(v.w);
    }
  }
  __syncthreads();
  {
    const int c = t >> 2, rs = (t & 3) * 16;
    u16* op = outp + ((size_t)e * C + (c0 + c)) * R + r0 + rs;
    uint4 o0, o1;
    o0.x = tile[rs + 0][c]  | ((unsigned)tile[rs + 1][c]  << 16);
    o0.y = tile[rs + 2][c]  | ((unsigned)tile[rs + 3][c]  << 16);
    o0.z = tile[rs + 4][c]  | ((unsigned)tile[rs + 5][c]  << 16);
    o0.w = tile[rs + 6][c]  | ((unsigned)tile[rs + 7][c]  << 16);
    o1.x = tile[rs + 8][c]  | ((unsigned)tile[rs + 9][c]  << 16);
    o1.y = tile[rs + 10][c] | ((unsigned)tile[rs + 11][c] << 16);
    o1.z = tile[rs + 12][c] | ((unsigned)tile[rs + 13][c] << 16);
    o1.w = tile[rs + 14][c] | ((unsigned)tile[rs + 15][c] << 16);
    *(uint4*)(op) = o0;
    *(uint4*)(op + 8) = o1;
  }
}

// ===================== bf16 GEMMs: BM128 x BN256, BK=32, 3-buf depth-2, 72KB LDS =====================
#define A_EL 4096      // 128*32 elems (8 KB)
#define B_EL 8192      // 256*32 elems (16 KB)

#define LDSW(base, row, hi4v) \
  (*(const bf16x8*)((const char*)(base) + (row) * 64 + ((((hi4v) ^ (((row) >> 1) & 3))) << 4)))

#define STG3(bs, k0) do { \
  gl16(aSrc + (k0), AsmF + (bs) * A_EL + wOff); \
  gl16(bSrc0 + (k0), BsmF + (bs) * B_EL + wOff); \
  gl16(bSrc1 + (k0), BsmF + (bs) * B_EL + wOff + 4096); \
} while (0)

__global__ __launch_bounds__(512, 4)
void fc1_bf(const u16* __restrict__ xb, const int* __restrict__ tok_idx,
            const u16* __restrict__ w1t, const float* __restrict__ b1,
            u16* __restrict__ h) {
  const int p = blockIdx.x;
  const int l = (p & 7) * 128 + (p >> 3);        // bijective XCD remap (1024 = 8*128)
  const int e  = l >> 4;
  const int mt = (l >> 2) & 3;
  const int nt = l & 3;
  const int m0 = mt * 128, n0 = nt * 256;
  const int t = threadIdx.x;
  const int lane = t & 63, wave = t >> 6;        // 8 waves
  const int wm = wave >> 2, wn = wave & 3;       // 2m x 4n, per-wave C 64x64

  __shared__ __align__(16) u16 SM[36864];        // 72 KB: staging; epilogue reuses 64 KB
  u16* AsmF = SM;                                // 3 * A_EL
  u16* BsmF = SM + 3 * A_EL;                     // 3 * B_EL

  const int kc = ((lane & 3) ^ ((lane >> 3) & 3)) * 8;  // pre-swizzled k elem offset
  const int rloc = lane >> 2;                    // 0..15
  const int wOff = wave * 512;                   // 16 rows x 32 elems

  const int arow = wave * 16 + rloc;             // 0..127
  const int tok = tok_idx[e * CAP + m0 + arow];
  const u16* aSrc  = xb + (size_t)tok * DIM + kc;
  const u16* bSrc0 = w1t + ((size_t)e * HID + n0 + arow) * DIM + kc;
  const u16* bSrc1 = w1t + ((size_t)e * HID + n0 + 128 + arow) * DIM + kc;

  f32x4 acc[4][4] = {};
  const int lr = lane & 15, hi4 = lane >> 4;

  STG3(0, 0);     // K-tile 0 -> buf 0
  STG3(1, 32);    // K-tile 1 -> buf 1
  int cur = 0;
  const int KT = DIM / 32;                       // 16
  for (int tt = 0; tt < KT; ++tt) {
    if (tt < KT - 1) asm volatile("s_waitcnt vmcnt(3)" ::: "memory");
    else             asm volatile("s_waitcnt vmcnt(0)" ::: "memory");
    __builtin_amdgcn_s_barrier();
    const u16* Ab = AsmF + cur * A_EL;
    const u16* Bb = BsmF + cur * B_EL;
    bf16x8 af[4], bf[4];
#pragma unroll
    for (int mi = 0; mi < 4; ++mi) af[mi] = LDSW(Ab, wm * 64 + mi * 16 + lr, hi4);
#pragma unroll
    for (int ni = 0; ni < 4; ++ni) bf[ni] = LDSW(Bb, wn * 64 + ni * 16 + lr, hi4);
    if (tt + 2 < KT) {
      const int bs = (tt + 2) % 3;
      STG3(bs, (tt + 2) * 32);
    }
    __builtin_amdgcn_s_setprio(1);
#pragma unroll
    for (int mi = 0; mi < 4; ++mi)
#pragma unroll
      for (int ni = 0; ni < 4; ++ni)
        acc[mi][ni] = __builtin_amdgcn_mfma_f32_16x16x32_bf16(af[mi], bf[ni], acc[mi][ni], 0, 0, 0);
    __builtin_amdgcn_s_setprio(0);
    __builtin_amdgcn_s_barrier();
    cur = cur == 2 ? 0 : cur + 1;
  }

  // ---- epilogue: gelu -> LDS tile [128][256] -> coalesced 512B-row writes ----
  const int lq = lane >> 4, lc = lane & 15;
#pragma unroll
  for (int nj = 0; nj < 4; ++nj) {
    const int n_l = wn * 64 + nj * 16 + lc;
    const float bias = b1[e * HID + n0 + n_l];
#pragma unroll
    for (int mi = 0; mi < 4; ++mi) {
#pragma unroll
      for (int j = 0; j < 4; ++j) {
        const int m_l = wm * 64 + mi * 16 + lq * 4 + j;
        SM[m_l * 256 + n_l] = f2bf(gelu_f(acc[mi][nj][j] + bias));
      }
    }
  }
  __syncthreads();
#pragma unroll
  for (int it = 0; it < 8; ++it) {
    const int cid = it * 512 + t;        // 16B chunk id, 32 chunks per row
    const int r = cid >> 5, c16 = cid & 31;
    uint4 v = *(const uint4*)(SM + r * 256 + c16 * 8);
    *(uint4*)(h + ((size_t)(e * CAP + m0 + r)) * HID + n0 + c16 * 8) = v;
  }
}

__global__ __launch_bounds__(512, 4)
void fc2_bf(const u16* __restrict__ h, const u16* __restrict__ w2t,
            const float* __restrict__ b2, const int* __restrict__ tok_idx,
            const float* __restrict__ expw, float* __restrict__ out) {
  const int p = blockIdx.x;
  const int l = (p & 7) * 64 + (p >> 3);         // bijective XCD remap (512 = 8*64)
  const int e  = l >> 3;
  const int mt = (l >> 1) & 3;
  const int nt = l & 1;
  const int m0 = mt * 128, n0 = nt * 256;
  const int t = threadIdx.x;
  const int lane = t & 63, wave = t >> 6;
  const int wm = wave >> 2, wn = wave & 3;

  __shared__ __align__(16) u16 SM[36864];
  u16* AsmF = SM;
  u16* BsmF = SM + 3 * A_EL;

  const int kc = ((lane & 3) ^ ((lane >> 3) & 3)) * 8;
  const int rloc = lane >> 2;
  const int wOff = wave * 512;

  const int arow = wave * 16 + rloc;
  const u16* aSrc  = h + ((size_t)(e * CAP + m0 + arow)) * HID + kc;
  const u16* bSrc0 = w2t + ((size_t)e * DIM + n0 + arow) * HID + kc;
  const u16* bSrc1 = w2t + ((size_t)e * DIM + n0 + 128 + arow) * HID + kc;

  f32x4 acc[4][4] = {};
  const int lr = lane & 15, hi4 = lane >> 4;

  STG3(0, 0);
  STG3(1, 32);
  int cur = 0;
  const int KT = HID / 32;                       // 32
  for (int tt = 0; tt < KT; ++tt) {
    if (tt < KT - 1) asm volatile("s_waitcnt vmcnt(3)" ::: "memory");
    else             asm volatile("s_waitcnt vmcnt(0)" ::: "memory");
    __builtin_amdgcn_s_barrier();
    const u16* Ab = AsmF + cur * A_EL;
    const u16* Bb = BsmF + cur * B_EL;
    bf16x8 af[4], bf[4];
#pragma unroll
    for (int mi = 0; mi < 4; ++mi) af[mi] = LDSW(Ab, wm * 64 + mi * 16 + lr, hi4);
#pragma unroll
    for (int ni = 0; ni < 4; ++ni) bf[ni] = LDSW(Bb, wn * 64 + ni * 16 + lr, hi4);
    if (tt + 2 < KT) {
      const int bs = (tt + 2) % 3;
      STG3(bs, (tt + 2) * 32);
    }
    __builtin_amdgcn_s_setprio(1);
#pragma unroll
    for (int mi = 0; mi < 4; ++mi)
#pragma unroll
      for (int ni = 0; ni < 4; ++ni)
        acc[mi][ni] = __builtin_amdgcn_mfma_f32_16x16x32_bf16(af[mi], bf[ni], acc[mi][ni], 0, 0, 0);
    __builtin_amdgcn_s_setprio(0);
    __builtin_amdgcn_s_barrier();
    cur = cur == 2 ? 0 : cur + 1;
  }

  const int lq = lane >> 4, lc = lane & 15;
  int   tokm[4][4];
  float wgt[4][4];
#pragma unroll
  for (int mi = 0; mi < 4; ++mi)
#pragma unroll
    for (int j = 0; j < 4; ++j) {
      const int m_l = wm * 64 + mi * 16 + lq * 4 + j;
      tokm[mi][j] = tok_idx[e * CAP + m0 + m_l];
      wgt[mi][j]  = expw[e * CAP + m0 + m_l];
    }
#pragma unroll
  for (int nj = 0; nj < 4; ++nj) {
    const int n_l = wn * 64 + nj * 16 + lc;
    const float bias = b2[e * DIM + n0 + n_l];
#pragma unroll
    for (int mi = 0; mi < 4; ++mi)
#pragma unroll
      for (int j = 0; j < 4; ++j) {
        float v = (acc[mi][nj][j] + bias) * wgt[mi][j];
        atomicAdd(out + (size_t)tokm[mi][j] * DIM + (n0 + n_l), v);
      }
  }
}

// ===================== fallback f32-input GEMMs (ws too small) =====================
#define SWZ(row, cb) ((cb) ^ (((((row) >> 3) ^ (row)) & 7) << 4))

__global__ __launch_bounds__(256)
void fc1_kernel(const float* __restrict__ x, const int* __restrict__ tok_idx,
                const float* __restrict__ w1, const float* __restrict__ b1,
                u16* __restrict__ h) {
  const int bx = blockIdx.x;
  const int e  = bx >> 5;
  const int mt = (bx >> 3) & 3;
  const int nt = bx & 7;
  const int m0 = mt * 128, n0 = nt * 128;
  const int t = threadIdx.x;
  const int lane = t & 63, wave = t >> 6;
  const int wm = wave >> 1, wn = wave & 1;

  __shared__ __align__(16) u16 Asm[128 * 64];
  __shared__ __align__(16) u16 Bsm[128 * 64];

  const int arq = t & 31, akq = t >> 5;
  int tokr[4];
#pragma unroll
  for (int j = 0; j < 4; ++j) tokr[j] = tok_idx[e * CAP + m0 + arq * 4 + j];
  const int nq = t & 31, kq = t >> 5;
  const float* bptr = w1 + (size_t)e * DIM * HID + n0 + nq * 4;

  f32x4 acc[4][4] = {};

  for (int k0 = 0; k0 < DIM; k0 += 64) {
    float4 av0[4], av1[4];
#pragma unroll
    for (int j = 0; j < 4; ++j) {
      const float* ap = x + (size_t)tokr[j] * DIM + k0 + akq * 8;
      av0[j] = *(const float4*)(ap);
      av1[j] = *(const float4*)(ap + 4);
    }
    float4 bv[8];
#pragma unroll
    for (int kk = 0; kk < 8; ++kk)
      bv[kk] = *(const float4*)(bptr + (size_t)(k0 + kq * 8 + kk) * HID);
    __syncthreads();
#pragma unroll
    for (int j = 0; j < 4; ++j) {
      const int row = arq * 4 + j;
      ushort4 w0, w1v;
      w0.x = f2bf(av0[j].x); w0.y = f2bf(av0[j].y); w0.z = f2bf(av0[j].z); w0.w = f2bf(av0[j].w);
      w1v.x = f2bf(av1[j].x); w1v.y = f2bf(av1[j].y); w1v.z = f2bf(av1[j].z); w1v.w = f2bf(av1[j].w);
      *(ushort4*)((char*)Asm + row * 128 + SWZ(row, (akq * 8 + 0) * 2)) = w0;
      *(ushort4*)((char*)Asm + row * 128 + SWZ(row, (akq * 8 + 4) * 2)) = w1v;
    }
#pragma unroll
    for (int g = 0; g < 2; ++g) {
#pragma unroll
      for (int j = 0; j < 4; ++j) {
        ushort4 wv;
        wv.x = f2bf(GET4(bv[g * 4 + 0], j));
        wv.y = f2bf(GET4(bv[g * 4 + 1], j));
        wv.z = f2bf(GET4(bv[g * 4 + 2], j));
        wv.w = f2bf(GET4(bv[g * 4 + 3], j));
        const int row = nq * 4 + j;
        const int cb = (kq * 8 + g * 4) * 2;
        *(ushort4*)((char*)Bsm + row * 128 + SWZ(row, cb)) = wv;
      }
    }
    __syncthreads();
#pragma unroll
    for (int ks = 0; ks < 2; ++ks) {
      bf16x8 af[4], bf[4];
#pragma unroll
      for (int mi = 0; mi < 4; ++mi) {
        const int row = wm * 64 + mi * 16 + (lane & 15);
        const int cb = ks * 64 + (lane >> 4) * 16;
        af[mi] = *(const bf16x8*)((const char*)Asm + row * 128 + SWZ(row, cb));
      }
#pragma unroll
      for (int ni = 0; ni < 4; ++ni) {
        const int row = wn * 64 + ni * 16 + (lane & 15);
        const int cb = ks * 64 + (lane >> 4) * 16;
        bf[ni] = *(const bf16x8*)((const char*)Bsm + row * 128 + SWZ(row, cb));
      }
#pragma unroll
      for (int mi = 0; mi < 4; ++mi)
#pragma unroll
        for (int ni = 0; ni < 4; ++ni)
          acc[mi][ni] = __builtin_amdgcn_mfma_f32_16x16x32_bf16(af[mi], bf[ni], acc[mi][ni], 0, 0, 0);
    }
  }
  const int lq = lane >> 4, lc = lane & 15;
#pragma unroll
  for (int ni = 0; ni < 4; ++ni) {
    const int n_l = wn * 64 + ni * 16 + lc;
    const float bias = b1[e * HID + n0 + n_l];
#pragma unroll
    for (int mi = 0; mi < 4; ++mi) {
#pragma unroll
      for (int j = 0; j < 4; ++j) {
        const int m_l = wm * 64 + mi * 16 + lq * 4 + j;
        float v = acc[mi][ni][j] + bias;
        h[((size_t)(e * CAP + m0 + m_l)) * HID + (n0 + n_l)] = f2bf(gelu_f(v));
      }
    }
  }
}

__global__ __launch_bounds__(256)
void fc2_kernel(const u16* __restrict__ h, const float* __restrict__ w2,
                const float* __restrict__ b2, const int* __restrict__ tok_idx,
                const float* __restrict__ expw, float* __restrict__ out) {
  const int bx = blockIdx.x;
  const int e  = bx >> 4;
  const int mt = (bx >> 2) & 3;
  const int nt = bx & 3;
  const int m0 = mt * 128, n0 = nt * 128;
  const int t = threadIdx.x;
  const int lane = t & 63, wave = t >> 6;
  const int wm = wave >> 1, wn = wave & 1;

  __shared__ __align__(16) u16 Asm[128 * 64];
  __shared__ __align__(16) u16 Bsm[128 * 64];

  const int arq = t & 31, akq = t >> 5;
  const u16* aptr0 = h + ((size_t)(e * CAP + m0 + arq * 4)) * HID + akq * 8;
  const int nq = t & 31, kq = t >> 5;
  const float* bptr = w2 + (size_t)e * HID * DIM + n0 + nq * 4;

  f32x4 acc[4][4] = {};

  for (int k0 = 0; k0 < HID; k0 += 64) {
    uint4 av[4];
#pragma unroll
    for (int j = 0; j < 4; ++j)
      av[j] = *(const uint4*)(aptr0 + (size_t)j * HID + k0);
    float4 bv[8];
#pragma unroll
    for (int kk = 0; kk < 8; ++kk)
      bv[kk] = *(const float4*)(bptr + (size_t)(k0 + kq * 8 + kk) * DIM);
    __syncthreads();
#pragma unroll
    for (int j = 0; j < 4; ++j) {
      const int row = arq * 4 + j;
      *(uint4*)((char*)Asm + row * 128 + SWZ(row, akq * 16)) = av[j];
    }
#pragma unroll
    for (int g = 0; g < 2; ++g) {
#pragma unroll
      for (int j = 0; j < 4; ++j) {
        ushort4 wv;
        wv.x = f2bf(GET4(bv[g * 4 + 0], j));
        wv.y = f2bf(GET4(bv[g * 4 + 1], j));
        wv.z = f2bf(GET4(bv[g * 4 + 2], j));
        wv.w = f2bf(GET4(bv[g * 4 + 3], j));
        const int row = nq * 4 + j;
        const int cb = (kq * 8 + g * 4) * 2;
        *(ushort4*)((char*)Bsm + row * 128 + SWZ(row, cb)) = wv;
      }
    }
    __syncthreads();
#pragma unroll
    for (int ks = 0; ks < 2; ++ks) {
      bf16x8 af[4], bf[4];
#pragma unroll
      for (int mi = 0; mi < 4; ++mi) {
        const int row = wm * 64 + mi * 16 + (lane & 15);
        const int cb = ks * 64 + (lane >> 4) * 16;
        af[mi] = *(const bf16x8*)((const char*)Asm + row * 128 + SWZ(row, cb));
      }
#pragma unroll
      for (int ni = 0; ni < 4; ++ni) {
        const int row = wn * 64 + ni * 16 + (lane & 15);
        const int cb = ks * 64 + (lane >> 4) * 16;
        bf[ni] = *(const bf16x8*)((const char*)Bsm + row * 128 + SWZ(row, cb));
      }
#pragma unroll
      for (int mi = 0; mi < 4; ++mi)
#pragma unroll
        for (int ni = 0; ni < 4; ++ni)
          acc[mi][ni] = __builtin_amdgcn_mfma_f32_16x16x32_bf16(af[mi], bf[ni], acc[mi][ni], 0, 0, 0);
    }
  }
  const int lq = lane >> 4, lc = lane & 15;
  int   tokm[4][4];
  float wgt[4][4];
#pragma unroll
  for (int mi = 0; mi < 4; ++mi)
#pragma unroll
    for (int j = 0; j < 4; ++j) {
      const int m_l = wm * 64 + mi * 16 + lq * 4 + j;
      tokm[mi][j] = tok_idx[e * CAP + m0 + m_l];
      wgt[mi][j]  = expw[e * CAP + m0 + m_l];
    }
#pragma unroll
  for (int ni = 0; ni < 4; ++ni) {
    const int n_l = wn * 64 + ni * 16 + lc;
    const float bias = b2[e * DIM + n0 + n_l];
#pragma unroll
    for (int mi = 0; mi < 4; ++mi)
#pragma unroll
      for (int j = 0; j < 4; ++j) {
        float v = (acc[mi][ni][j] + bias) * wgt[mi][j];
        atomicAdd(out + (size_t)tokm[mi][j] * DIM + (n0 + n_l), v);
      }
  }
}

extern "C" void kernel_launch(void* const* d_in, const int* in_sizes, int n_in,
                              void* d_out, int out_size, void* d_ws, size_t ws_size,
                              hipStream_t stream) {
  const float* x  = (const float*)d_in[0];
  const float* rw = (const float*)d_in[1];
  const float* w1 = (const float*)d_in[2];
  const float* b1 = (const float*)d_in[3];
  const float* w2 = (const float*)d_in[4];
  const float* b2 = (const float*)d_in[5];
  float* out = (float*)d_out;

  char* ws = (char*)d_ws;
  const size_t MB = 1u << 20;
  float* logits = (float*)ws;                                   // [0, 8M)
  int*   toki   = (int*)(ws + 8 * MB);                          // 128 KB
  float* ew     = (float*)(ws + 8 * MB + (128u << 10));         // 128 KB

  const size_t off_xb = 8 * MB + (256u << 10);   // 8.25M
  const size_t off_wt = off_xb + 32 * MB;        // 40.25M
  const size_t off_h  = off_wt + 64 * MB;        // 104.25M
  const size_t need   = off_h + 64 * MB;         // 168.25M
  const bool big = (ws_size >= need);

  // topk scratch: ghist(64KB) + psum(4KB); lives in h region (consumed before fc1 writes h)
  const size_t off_meta = big ? off_h : (8 * MB + (256u << 10));
  u32*   ghist = (u32*)(ws + off_meta);                    // 64 KB (64 x 256 x u32)
  float* psum  = (float*)(ws + off_meta + (64u << 10));    // 4 KB

  u16* xb = big ? (u16*)(ws + off_xb) : (u16*)0;

  (void)hipMemsetAsync(d_out, 0, (size_t)out_size * sizeof(float), stream);
  (void)hipMemsetAsync(ws + off_meta, 0, 68u << 10, stream);
  router_kernel<<<dim3(512), dim3(256), 0, stream>>>(x, rw, logits, xb);
  topk_hist<<<dim3(16, 64), dim3(256), 0, stream>>>(logits, ghist, psum);
  topk_selemit<<<dim3(64), dim3(256), 0, stream>>>(logits, ghist, psum, toki, ew,
                                                   out + (size_t)N_TOK * DIM);

  if (big) {
    u16* wt  = (u16*)(ws + off_wt);
    u16* h   = (u16*)(ws + off_h);
    transpose_cvt_kernel<<<dim3(16, 8, 64), dim3(256), 0, stream>>>(w1, wt, 512, 1024);
    fc1_bf<<<dim3(1024), dim3(512), 0, stream>>>(xb, toki, wt, b1, h);
    transpose_cvt_kernel<<<dim3(8, 16, 64), dim3(256), 0, stream>>>(w2, wt, 1024, 512);
    fc2_bf<<<dim3(512), dim3(512), 0, stream>>>(h, wt, b2, toki, ew, out);
  } else {
    u16* h = (u16*)(ws + 8 * MB + (512u << 10)); // after meta in fallback layout
    fc1_kernel<<<dim3(2048), dim3(256), 0, stream>>>(x, toki, w1, b1, h);
    fc2_kernel<<<dim3(1024), dim3(256), 0, stream>>>(h, w2, b2, toki, ew, out);
  }
}